// Round 1
// baseline (489.623 us; speedup 1.0000x reference)
//
#include <hip/hip_runtime.h>
#include <hip/hip_bf16.h>

// ---------------------------------------------------------------------------
// NonLocal block + FC, MI355X (gfx950).
//
// Algebraic reduction: out = (mean_n(x) + w_w @ ybar + w_b) @ fc_w^T + fc_b
//   ybar[b,d] = g_w[d,:] @ xg[b,:] + g_b[d]
//   xg[b,c]   = sum_n abar[b,n] * x[b,c,n]
//   abar[b,m] = mean_n softmax_row_n(f)[m],  f = theta @ phi^T
// Only theta/phi projections (K=1024) and f (K=512) are heavy -> bf16 MFMA.
// ---------------------------------------------------------------------------

#define BATCH 16
#define CIN   1024
#define CINT  512
#define NSP   1568      // T*H*W = 8*14*14
#define NPAD  1664      // 13*128  (padded rows; pad contents are garbage but
                        //  provably never contaminate real outputs)
#define NCLS  13

using bf16 = __hip_bfloat16;
typedef __attribute__((ext_vector_type(8))) short short8;
typedef __attribute__((ext_vector_type(4))) float f32x4;

#define DEVI static __device__ __forceinline__

DEVI void gload16(const void* g, void* l) {
  __builtin_amdgcn_global_load_lds((const __attribute__((address_space(1))) void*)g,
                                   (__attribute__((address_space(3))) void*)l, 16, 0, 0);
}

DEVI float wave_sum(float v) {
#pragma unroll
  for (int m = 32; m; m >>= 1) v += __shfl_xor(v, m);
  return v;
}
DEVI float wave_max(float v) {
#pragma unroll
  for (int m = 32; m; m >>= 1) v = fmaxf(v, __shfl_xor(v, m));
  return v;
}

// ---------------- K1: x[b][c][n] fp32 -> xt[b][n][c] bf16 (transpose) -------
__global__ void k_transpose(const float* __restrict__ x, bf16* __restrict__ xt) {
  __shared__ float t[32][33];
  const int b = blockIdx.z;
  const int n0 = blockIdx.x * 32;   // 49 tiles * 32 = 1568 exact
  const int c0 = blockIdx.y * 32;   // 32 tiles * 32 = 1024 exact
  const int tx = threadIdx.x;       // 0..31
  const int ty = threadIdx.y;       // 0..7
  const float* xb = x + (size_t)b * CIN * NSP;
#pragma unroll
  for (int j = 0; j < 4; ++j) {
    const int c = c0 + ty + j * 8;
    t[ty + j * 8][tx] = xb[(size_t)c * NSP + n0 + tx];
  }
  __syncthreads();
  bf16* xo = xt + (size_t)b * NPAD * CIN;
#pragma unroll
  for (int j = 0; j < 4; ++j) {
    const int n = n0 + ty + j * 8;
    xo[(size_t)n * CIN + c0 + tx] = __float2bfloat16(t[tx][ty + j * 8]);
  }
}

// ---------------- K1b: theta_w / phi_w fp32 -> wb bf16 [1024][1024] ---------
__global__ void k_wconv(const float* __restrict__ thw, const float* __restrict__ phw,
                        bf16* __restrict__ wb) {
  const int i4 = (blockIdx.x * 256 + threadIdx.x) * 4;   // 1024 blocks
  const float* s = (i4 < 512 * 1024) ? (thw + i4) : (phw + (i4 - 512 * 1024));
  const float4 v = *(const float4*)s;
  wb[i4 + 0] = __float2bfloat16(v.x);
  wb[i4 + 1] = __float2bfloat16(v.y);
  wb[i4 + 2] = __float2bfloat16(v.z);
  wb[i4 + 3] = __float2bfloat16(v.w);
}

// ---------------- K2: xbar[b][c] = mean_n x[b][c][n] ------------------------
__global__ void k_xbar(const float* __restrict__ x, float* __restrict__ xbar) {
  const int id = blockIdx.x * 4 + (threadIdx.x >> 6);  // b*1024+c, 16384 rows
  const int lane = threadIdx.x & 63;
  const float4* r = (const float4*)(x + (size_t)id * NSP);
  float s = 0.f;
#pragma unroll
  for (int k = 0; k < 7; ++k) {
    const int i = lane + k * 64;
    if (i < 392) { const float4 v = r[i]; s += v.x + v.y + v.z + v.w; }
  }
  s = wave_sum(s);
  if (lane == 0) xbar[id] = s * (1.0f / NSP);
}

// ---------------- shared 128x128 bf16 BT-GEMM core (m97 structure) ----------
template <int LDK>
DEVI void gemm128_bt(const bf16* Ag, const bf16* Bg, bf16* lA, bf16* lB,
                     f32x4 acc[4][4]) {
  const int tid = threadIdx.x;
  const int lane = tid & 63;
  const int w = tid >> 6;
  const int wr = (w >> 1) * 64;
  const int wc = (w & 1) * 64;
#pragma unroll 1
  for (int ks = 0; ks < LDK / 32; ++ks) {
#pragma unroll
    for (int it = 0; it < 2; ++it) {
      const int ch = w * 64 + it * 256 + lane;       // chunk 0..511
      const int row = ch >> 2;
      const int kc = ch & 3;
      const int lbase = (w * 64 + it * 256) * 8;     // wave-uniform LDS base
      gload16(Ag + (size_t)row * LDK + ks * 32 + kc * 8, lA + lbase);
      gload16(Bg + (size_t)row * LDK + ks * 32 + kc * 8, lB + lbase);
    }
    __syncthreads();
    short8 af[4], bfr[4];
#pragma unroll
    for (int i = 0; i < 4; ++i)
      af[i] = *(const short8*)(lA + (wr + i * 16 + (lane & 15)) * 32 + (lane >> 4) * 8);
#pragma unroll
    for (int i = 0; i < 4; ++i)
      bfr[i] = *(const short8*)(lB + (wc + i * 16 + (lane & 15)) * 32 + (lane >> 4) * 8);
#pragma unroll
    for (int m = 0; m < 4; ++m)
#pragma unroll
      for (int n = 0; n < 4; ++n)
        acc[m][n] = __builtin_amdgcn_mfma_f32_16x16x32_bf16(af[m], bfr[n], acc[m][n], 0, 0, 0);
    __syncthreads();
  }
}

// ---------------- K3: theta/phi projections ---------------------------------
// grid (208, 8): x-tiles over 16*1664 padded rows, y: 0-3 theta / 4-7 phi
__global__ __launch_bounds__(256) void k_proj(const bf16* __restrict__ xt,
                                              const bf16* __restrict__ wb,
                                              const float* __restrict__ thb,
                                              const float* __restrict__ phb,
                                              bf16* __restrict__ th,
                                              bf16* __restrict__ ph) {
  __shared__ bf16 lA[128 * 32], lB[128 * 32];
  const int bm = blockIdx.x;
  const int bo = blockIdx.y;
  f32x4 acc[4][4];
  const f32x4 z = {0.f, 0.f, 0.f, 0.f};
#pragma unroll
  for (int m = 0; m < 4; ++m)
#pragma unroll
    for (int n = 0; n < 4; ++n) acc[m][n] = z;

  gemm128_bt<CIN>(xt + (size_t)bm * 128 * CIN, wb + (size_t)bo * 128 * CIN, lA, lB, acc);

  const int lane = threadIdx.x & 63;
  const int w = threadIdx.x >> 6;
  const int wr = (w >> 1) * 64;
  const int wc = (w & 1) * 64;
  bf16* outb = (bo < 4) ? th : ph;
  const float* bias = (bo < 4) ? thb : phb;
  const int obase = (bo & 3) * 128;
#pragma unroll
  for (int m = 0; m < 4; ++m)
#pragma unroll
    for (int n = 0; n < 4; ++n) {
      const int o = obase + wc + n * 16 + (lane & 15);
      const float bv = bias[o];
#pragma unroll
      for (int j = 0; j < 4; ++j) {
        const int R = bm * 128 + wr + m * 16 + (lane >> 4) * 4 + j;
        outb[(size_t)R * CINT + o] = __float2bfloat16(acc[m][n][j] + bv);
      }
    }
}

// ---------------- K4: f = theta @ phi^T per batch ---------------------------
// grid (13, 13, 16)
__global__ __launch_bounds__(256) void k_fgemm(const bf16* __restrict__ th,
                                               const bf16* __restrict__ ph,
                                               float* __restrict__ f) {
  __shared__ bf16 lA[128 * 32], lB[128 * 32];
  const int bm = blockIdx.x, bn = blockIdx.y, b = blockIdx.z;
  f32x4 acc[4][4];
  const f32x4 z = {0.f, 0.f, 0.f, 0.f};
#pragma unroll
  for (int m = 0; m < 4; ++m)
#pragma unroll
    for (int n = 0; n < 4; ++n) acc[m][n] = z;

  gemm128_bt<CINT>(th + ((size_t)b * NPAD + bm * 128) * CINT,
                   ph + ((size_t)b * NPAD + bn * 128) * CINT, lA, lB, acc);

  const int lane = threadIdx.x & 63;
  const int w = threadIdx.x >> 6;
  const int wr = (w >> 1) * 64;
  const int wc = (w & 1) * 64;
  float* fb = f + (size_t)b * NPAD * NPAD;
#pragma unroll
  for (int m = 0; m < 4; ++m)
#pragma unroll
    for (int n = 0; n < 4; ++n) {
      const int col = bn * 128 + wc + n * 16 + (lane & 15);
#pragma unroll
      for (int j = 0; j < 4; ++j) {
        const int R = bm * 128 + wr + m * 16 + (lane >> 4) * 4 + j;
        fb[(size_t)R * NPAD + col] = acc[m][n][j];
      }
    }
}

// ---------------- K5: per-row max and inverse expsum (cols m < 1568) --------
__global__ void k_rowstats(const float* __restrict__ f, float* __restrict__ rmax,
                           float* __restrict__ rsinv) {
  const int id = blockIdx.x * 4 + (threadIdx.x >> 6);  // 0..25087
  const int lane = threadIdx.x & 63;
  const int b = id / NSP;
  const int n = id - b * NSP;
  const float4* row = (const float4*)(f + ((size_t)b * NPAD + n) * NPAD);
  float4 vals[7];
  float mx = -3.4e38f;
#pragma unroll
  for (int k = 0; k < 7; ++k) {
    const int i = lane + k * 64;
    if (i < 392) {
      const float4 v = row[i];
      vals[k] = v;
      mx = fmaxf(mx, fmaxf(fmaxf(v.x, v.y), fmaxf(v.z, v.w)));
    }
  }
  mx = wave_max(mx);
  float s = 0.f;
#pragma unroll
  for (int k = 0; k < 7; ++k) {
    const int i = lane + k * 64;
    if (i < 392) {
      const float4 v = vals[k];
      s += __expf(v.x - mx) + __expf(v.y - mx) + __expf(v.z - mx) + __expf(v.w - mx);
    }
  }
  s = wave_sum(s);
  if (lane == 0) { rmax[id] = mx; rsinv[id] = 1.0f / s; }
}

// ---------------- K6: abar[b][m] = mean_n attn[n][m] ------------------------
// grid (7, 8, 16): 7 col-chunks of 256, 8 row-slices of 196, 16 batches
__global__ void k_abar(const float* __restrict__ f, const float* __restrict__ rmax,
                       const float* __restrict__ rsinv, float* __restrict__ abar) {
  const int m = blockIdx.x * 256 + threadIdx.x;
  const int b = blockIdx.z;
  const bool act = m < NSP;
  const float* fb = f + (size_t)b * NPAD * NPAD;
  const int n0 = blockIdx.y * 196;
  float local = 0.f;
  for (int n = n0; n < n0 + 196; ++n) {
    const float Mn = rmax[b * NSP + n];
    const float iS = rsinv[b * NSP + n];
    if (act) local += __expf(fb[(size_t)n * NPAD + m] - Mn) * iS;
  }
  if (act) atomicAdd(&abar[b * NSP + m], local * (1.0f / NSP));
}

// ---------------- K7: xg[b][c] = sum_n abar[b][n] * x[b][c][n] --------------
__global__ void k_xg(const float* __restrict__ x, const float* __restrict__ abar,
                     float* __restrict__ xg) {
  const int id = blockIdx.x * 4 + (threadIdx.x >> 6);  // b*1024+c
  const int lane = threadIdx.x & 63;
  const int b = id >> 10;
  const float4* xr = (const float4*)(x + (size_t)id * NSP);
  const float4* ar = (const float4*)(abar + (size_t)b * NSP);
  float s = 0.f;
#pragma unroll
  for (int k = 0; k < 7; ++k) {
    const int i = lane + k * 64;
    if (i < 392) {
      const float4 xv = xr[i];
      const float4 av = ar[i];
      s += xv.x * av.x + xv.y * av.y + xv.z * av.z + xv.w * av.w;
    }
  }
  s = wave_sum(s);
  if (lane == 0) xg[id] = s;
}

// ---------------- K8: head (all fp32, tiny) ---------------------------------
__global__ __launch_bounds__(256) void k_head(const float* __restrict__ xg,
                                              const float* __restrict__ xbar,
                                              const float* __restrict__ gw,
                                              const float* __restrict__ gb,
                                              const float* __restrict__ ww,
                                              const float* __restrict__ wbias,
                                              const float* __restrict__ fcw,
                                              const float* __restrict__ fcb,
                                              float* __restrict__ out) {
  const int b = blockIdx.x;
  const int tid = threadIdx.x;
  __shared__ float sxg[CIN], syb[CINT], spool[CIN];
  for (int i = tid; i < CIN; i += 256) sxg[i] = xg[b * CIN + i];
  __syncthreads();
  for (int d = tid; d < CINT; d += 256) {
    float a = gb[d];
    const float4* wr = (const float4*)(gw + (size_t)d * CIN);
    for (int c4 = 0; c4 < CIN / 4; ++c4) {
      const float4 w4 = wr[c4];
      const float* xs = &sxg[c4 * 4];
      a += w4.x * xs[0] + w4.y * xs[1] + w4.z * xs[2] + w4.w * xs[3];
    }
    syb[d] = a;
  }
  __syncthreads();
  for (int c = tid; c < CIN; c += 256) {
    float a = wbias[c] + xbar[b * CIN + c];
    const float4* wr = (const float4*)(ww + (size_t)c * CINT);
    for (int d4 = 0; d4 < CINT / 4; ++d4) {
      const float4 w4 = wr[d4];
      const float* ys = &syb[d4 * 4];
      a += w4.x * ys[0] + w4.y * ys[1] + w4.z * ys[2] + w4.w * ys[3];
    }
    spool[c] = a;
  }
  __syncthreads();
  if (tid < NCLS) {
    float a = fcb[tid];
    const float4* wr = (const float4*)(fcw + (size_t)tid * CIN);
    for (int c4 = 0; c4 < CIN / 4; ++c4) {
      const float4 w4 = wr[c4];
      const float* ps = &spool[c4 * 4];
      a += w4.x * ps[0] + w4.y * ps[1] + w4.z * ps[2] + w4.w * ps[3];
    }
    out[b * NCLS + tid] = a;
  }
}

// ---------------------------------------------------------------------------
extern "C" void kernel_launch(void* const* d_in, const int* in_sizes, int n_in,
                              void* d_out, int out_size, void* d_ws, size_t ws_size,
                              hipStream_t stream) {
  const float* x    = (const float*)d_in[0];
  const float* g_w  = (const float*)d_in[1];
  const float* g_b  = (const float*)d_in[2];
  const float* th_w = (const float*)d_in[3];
  const float* th_b = (const float*)d_in[4];
  const float* ph_w = (const float*)d_in[5];
  const float* ph_b = (const float*)d_in[6];
  const float* w_w  = (const float*)d_in[7];
  const float* w_b  = (const float*)d_in[8];
  const float* fc_w = (const float*)d_in[9];
  const float* fc_b = (const float*)d_in[10];
  float* out = (float*)d_out;

  // ws carve-out (~289 MB total)
  char* ws = (char*)d_ws;
  size_t off = 0;
  auto carve = [&](size_t bytes) {
    void* p = ws + off;
    off = (off + bytes + 255) & ~(size_t)255;
    return p;
  };
  bf16*  xt    = (bf16*)carve((size_t)BATCH * NPAD * CIN * 2);
  bf16*  wb    = (bf16*)carve((size_t)1024 * 1024 * 2);
  bf16*  th    = (bf16*)carve((size_t)BATCH * NPAD * CINT * 2);
  bf16*  ph    = (bf16*)carve((size_t)BATCH * NPAD * CINT * 2);
  float* f     = (float*)carve((size_t)BATCH * NPAD * NPAD * 4);
  float* rmax  = (float*)carve((size_t)BATCH * NSP * 4);
  float* rsinv = (float*)carve((size_t)BATCH * NSP * 4);
  float* abar  = (float*)carve((size_t)BATCH * NSP * 4);
  float* xbar  = (float*)carve((size_t)BATCH * CIN * 4);
  float* xg    = (float*)carve((size_t)BATCH * CIN * 4);
  (void)ws_size; (void)in_sizes; (void)n_in; (void)out_size;

  hipMemsetAsync(abar, 0, (size_t)BATCH * NSP * 4, stream);

  k_transpose<<<dim3(49, 32, 16), dim3(32, 8), 0, stream>>>(x, xt);
  k_wconv<<<1024, 256, 0, stream>>>(th_w, ph_w, wb);
  k_xbar<<<4096, 256, 0, stream>>>(x, xbar);
  k_proj<<<dim3(208, 8), 256, 0, stream>>>(xt, wb, th_b, ph_b, th, ph);
  k_fgemm<<<dim3(13, 13, 16), 256, 0, stream>>>(th, ph, f);
  k_rowstats<<<6272, 256, 0, stream>>>(f, rmax, rsinv);
  k_abar<<<dim3(7, 8, 16), 256, 0, stream>>>(f, rmax, rsinv, abar);
  k_xg<<<4096, 256, 0, stream>>>(x, abar, xg);
  k_head<<<16, 256, 0, stream>>>(xg, xbar, g_w, g_b, w_w, w_b, fc_w, fc_b, out);
}

// Round 4
// 355.743 us; speedup vs baseline: 1.3763x; 1.3763x over previous
//
#include <hip/hip_runtime.h>
#include <hip/hip_bf16.h>

// ---------------------------------------------------------------------------
// NonLocal block + FC, MI355X (gfx950).
// out = (mean_n(x) + w_w @ ybar + w_b) @ fc_w^T + fc_b
//   ybar = g_w @ xg + g_b ;  xg[b,c] = sum_n abar[b,n] x[b,c,n]
//   abar[b,m] = mean_n softmax_row(f)[n,m],  f = theta @ phi^T
// |f| <~ 60 -> exp without max-subtraction is fp32-safe; e stored bf16.
// ---------------------------------------------------------------------------

#define BATCH 16
#define CIN   1024
#define CINT  512
#define NSP   1568      // 8*14*14
#define NPAD  1664      // 13*128
#define NTIL  13
#define NCLS  13

using bf16 = __hip_bfloat16;
typedef __attribute__((ext_vector_type(8))) short short8;
typedef __attribute__((ext_vector_type(4))) float f32x4;

#define DEVI static __device__ __forceinline__

DEVI void gload16(const void* g, void* l) {
  __builtin_amdgcn_global_load_lds((const __attribute__((address_space(1))) void*)g,
                                   (__attribute__((address_space(3))) void*)l, 16, 0, 0);
}

DEVI float wave_sum(float v) {
#pragma unroll
  for (int m = 32; m; m >>= 1) v += __shfl_xor(v, m);
  return v;
}

DEVI short f2bf(float f) {
  union { __hip_bfloat16 h; short s; } u;
  u.h = __float2bfloat16(f);
  return u.s;
}

// ---- K1: transpose x[b][c][n] fp32 -> xt[b][n][c] bf16, fused xbar ---------
// grid (52, 8, 16) block 256. n-tiles >= 49 are all-pad (zero-filled).
__global__ __launch_bounds__(256) void k_transpose(const float* __restrict__ x,
                                                   bf16* __restrict__ xt,
                                                   float* __restrict__ xbar) {
  __shared__ float t[128 * 37];
  const int b = blockIdx.z;
  const int n0 = blockIdx.x * 32;
  const int c0 = blockIdx.y * 128;
  const int tid = threadIdx.x;
  const int lane = tid & 63;
  const float* xb = x + (size_t)b * CIN * NSP;
  const bool pad = (n0 >= NSP);
#pragma unroll
  for (int it = 0; it < 4; ++it) {
    const int slot = it * 256 + tid;
    const int cr = slot >> 3;       // 0..127
    const int q = slot & 7;         // 0..7
    float4 v = {0.f, 0.f, 0.f, 0.f};
    if (!pad) v = *(const float4*)(xb + (size_t)(c0 + cr) * NSP + n0 + q * 4);
    t[cr * 37 + q * 4 + 0] = v.x;
    t[cr * 37 + q * 4 + 1] = v.y;
    t[cr * 37 + q * 4 + 2] = v.z;
    t[cr * 37 + q * 4 + 3] = v.w;
    // fused xbar partial: reduce over the 8 q-lanes (lane bits 0..2)
    float s = v.x + v.y + v.z + v.w;
    s += __shfl_xor(s, 1);
    s += __shfl_xor(s, 2);
    s += __shfl_xor(s, 4);
    if ((lane & 7) == 0 && !pad)
      atomicAdd(&xbar[b * CIN + c0 + cr], s * (1.0f / NSP));
  }
  __syncthreads();
  bf16* xo = xt + (size_t)b * NPAD * CIN;
#pragma unroll
  for (int it = 0; it < 2; ++it) {
    const int slot = it * 256 + tid;
    const int n = slot >> 4;        // 0..31
    const int seg = slot & 15;      // 0..15
    short8 o;
#pragma unroll
    for (int k = 0; k < 8; ++k) o[k] = f2bf(t[(seg * 8 + k) * 37 + n]);
    *(short8*)(xo + (size_t)(n0 + n) * CIN + c0 + seg * 8) = o;
  }
}

// ---- K1b: theta_w / phi_w fp32 -> wb bf16 [1024][1024] ---------------------
__global__ void k_wconv(const float* __restrict__ thw, const float* __restrict__ phw,
                        bf16* __restrict__ wb) {
  const int i4 = (blockIdx.x * 256 + threadIdx.x) * 4;
  const float* s = (i4 < 512 * 1024) ? (thw + i4) : (phw + (i4 - 512 * 1024));
  const float4 v = *(const float4*)s;
  wb[i4 + 0] = __float2bfloat16(v.x);
  wb[i4 + 1] = __float2bfloat16(v.y);
  wb[i4 + 2] = __float2bfloat16(v.z);
  wb[i4 + 3] = __float2bfloat16(v.w);
}

// ---- shared 128x128 bf16 BT-GEMM core (m97 structure) ----------------------
template <int LDK>
DEVI void gemm128_bt(const bf16* Ag, const bf16* Bg, bf16* lA, bf16* lB,
                     f32x4 acc[4][4]) {
  const int tid = threadIdx.x;
  const int lane = tid & 63;
  const int w = tid >> 6;
  const int wr = (w >> 1) * 64;
  const int wc = (w & 1) * 64;
#pragma unroll 1
  for (int ks = 0; ks < LDK / 32; ++ks) {
#pragma unroll
    for (int it = 0; it < 2; ++it) {
      const int ch = w * 64 + it * 256 + lane;
      const int row = ch >> 2;
      const int kc = ch & 3;
      const int lbase = (w * 64 + it * 256) * 8;
      gload16(Ag + (size_t)row * LDK + ks * 32 + kc * 8, lA + lbase);
      gload16(Bg + (size_t)row * LDK + ks * 32 + kc * 8, lB + lbase);
    }
    __syncthreads();
    short8 af[4], bfr[4];
#pragma unroll
    for (int i = 0; i < 4; ++i)
      af[i] = *(const short8*)(lA + (wr + i * 16 + (lane & 15)) * 32 + (lane >> 4) * 8);
#pragma unroll
    for (int i = 0; i < 4; ++i)
      bfr[i] = *(const short8*)(lB + (wc + i * 16 + (lane & 15)) * 32 + (lane >> 4) * 8);
#pragma unroll
    for (int m = 0; m < 4; ++m)
#pragma unroll
      for (int n = 0; n < 4; ++n)
        acc[m][n] = __builtin_amdgcn_mfma_f32_16x16x32_bf16(af[m], bfr[n], acc[m][n], 0, 0, 0);
    __syncthreads();
  }
}

// ---- K3: theta/phi projections. grid (8, 208): x = bo, y = bm --------------
__global__ __launch_bounds__(256) void k_proj(const bf16* __restrict__ xt,
                                              const bf16* __restrict__ wb,
                                              const float* __restrict__ thb,
                                              const float* __restrict__ phb,
                                              bf16* __restrict__ th,
                                              bf16* __restrict__ ph) {
  __shared__ bf16 smem[16384];   // lA|lB during GEMM, 128x128 bf16 stage after
  const int bo = blockIdx.x;
  const int bm = blockIdx.y;
  f32x4 acc[4][4];
  const f32x4 z = {0.f, 0.f, 0.f, 0.f};
#pragma unroll
  for (int m = 0; m < 4; ++m)
#pragma unroll
    for (int n = 0; n < 4; ++n) acc[m][n] = z;

  gemm128_bt<CIN>(xt + (size_t)bm * 128 * CIN, wb + (size_t)bo * 128 * CIN,
                  smem, smem + 4096, acc);

  const int tid = threadIdx.x;
  const int lane = tid & 63;
  const int w = tid >> 6;
  const int wr = (w >> 1) * 64;
  const int wc = (w & 1) * 64;
  const float* bias = (bo < 4) ? thb : phb;
  bf16* outb = (bo < 4) ? th : ph;
  const int obase = (bo & 3) * 128;
  __syncthreads();
  // stage to [128][128] (xor-swizzled segs) for coalesced writes
#pragma unroll
  for (int m = 0; m < 4; ++m)
#pragma unroll
    for (int n = 0; n < 4; ++n) {
      const int col_l = wc + n * 16 + (lane & 15);
      const float bv = bias[obase + col_l];
#pragma unroll
      for (int j = 0; j < 4; ++j) {
        const int row_l = wr + m * 16 + (lane >> 4) * 4 + j;
        smem[row_l * 128 + (col_l ^ ((row_l & 7) << 3))] =
            __float2bfloat16(acc[m][n][j] + bv);
      }
    }
  __syncthreads();
#pragma unroll
  for (int it = 0; it < 8; ++it) {
    const int slot = it * 256 + tid;
    const int r = slot >> 4;
    const int seg = slot & 15;
    const short8 v = *(const short8*)(smem + r * 128 + ((seg ^ (r & 7)) << 3));
    *(short8*)(outb + (size_t)(bm * 128 + r) * CINT + obase + seg * 8) = v;
  }
}

// ---- K4: e = exp(theta @ phi^T) bf16 + per-tile row sums -------------------
// grid (13, 13, 16): x = bn (fastest, shares A-tile), y = bm, z = b
__global__ __launch_bounds__(256) void k_fgemm(const bf16* __restrict__ th,
                                               const bf16* __restrict__ ph,
                                               bf16* __restrict__ eb,
                                               float* __restrict__ psum) {
  __shared__ bf16 smem[16384];
  __shared__ float rsum2[2][128];
  const int bn = blockIdx.x, bm = blockIdx.y, b = blockIdx.z;
  f32x4 acc[4][4];
  const f32x4 z = {0.f, 0.f, 0.f, 0.f};
#pragma unroll
  for (int m = 0; m < 4; ++m)
#pragma unroll
    for (int n = 0; n < 4; ++n) acc[m][n] = z;

  gemm128_bt<CINT>(th + ((size_t)b * NPAD + bm * 128) * CINT,
                   ph + ((size_t)b * NPAD + bn * 128) * CINT,
                   smem, smem + 4096, acc);

  const int tid = threadIdx.x;
  const int lane = tid & 63;
  const int w = tid >> 6;
  const int wr = (w >> 1) * 64;
  const int wc = (w & 1) * 64;
  __syncthreads();
#pragma unroll
  for (int m = 0; m < 4; ++m)
#pragma unroll
    for (int j = 0; j < 4; ++j) {
      const int row_l = wr + m * 16 + (lane >> 4) * 4 + j;
      float ps = 0.f;
#pragma unroll
      for (int n = 0; n < 4; ++n) {
        const int col_l = wc + n * 16 + (lane & 15);
        const float ev = __expf(acc[m][n][j]);
        smem[row_l * 128 + (col_l ^ ((row_l & 7) << 3))] = __float2bfloat16(ev);
        if (bn * 128 + col_l < NSP) ps += ev;   // mask pad columns
      }
      ps += __shfl_xor(ps, 1);
      ps += __shfl_xor(ps, 2);
      ps += __shfl_xor(ps, 4);
      ps += __shfl_xor(ps, 8);
      if ((lane & 15) == 0) rsum2[w & 1][row_l] = ps;
    }
  __syncthreads();
  if (tid < 128)
    psum[((size_t)b * NTIL + bn) * NPAD + bm * 128 + tid] =
        rsum2[0][tid] + rsum2[1][tid];
  bf16* ebb = eb + ((size_t)b * NPAD + bm * 128) * NPAD + bn * 128;
#pragma unroll
  for (int it = 0; it < 8; ++it) {
    const int slot = it * 256 + tid;
    const int r = slot >> 4;
    const int seg = slot & 15;
    const short8 v = *(const short8*)(smem + r * 128 + ((seg ^ (r & 7)) << 3));
    *(short8*)(ebb + (size_t)r * NPAD + seg * 8) = v;
  }
}

// ---- K5: rinv[b][n] = 1 / sum_t psum[b][t][n] ------------------------------
__global__ void k_recip(const float* __restrict__ psum, float* __restrict__ rinv) {
  const int id = blockIdx.x * 256 + threadIdx.x;   // 98*256 == 25088 exact
  const int b = id / NSP;
  const int n = id - b * NSP;
  float s = 0.f;
#pragma unroll
  for (int t = 0; t < NTIL; ++t) s += psum[((size_t)b * NTIL + t) * NPAD + n];
  rinv[id] = 1.0f / s;
}

// ---- K6: abar[b][m] = (1/N) sum_n e[n,m] * rinv[n] -------------------------
// grid (7, 8, 16)
__global__ void k_abar(const bf16* __restrict__ eb, const float* __restrict__ rinv,
                       float* __restrict__ abar) {
  const int m = blockIdx.x * 256 + threadIdx.x;
  const int b = blockIdx.z;
  const bool act = m < NSP;
  const bf16* fb = eb + (size_t)b * NPAD * NPAD;
  const int n0 = blockIdx.y * 196;
  float local = 0.f;
  for (int n = n0; n < n0 + 196; ++n) {
    const float iS = rinv[b * NSP + n];
    if (act) local += __bfloat162float(fb[(size_t)n * NPAD + m]) * iS;
  }
  if (act) atomicAdd(&abar[b * NSP + m], local * (1.0f / NSP));
}

// ---- K7: xg[b][c] = sum_n abar[b][n] * xt[b][n][c]  (bf16 source) ----------
// grid (4, 8, 16)
__global__ void k_xg(const bf16* __restrict__ xt, const float* __restrict__ abar,
                     float* __restrict__ xg) {
  const int c = blockIdx.x * 256 + threadIdx.x;
  const int b = blockIdx.z;
  const bf16* xb = xt + (size_t)b * NPAD * CIN;
  const int n0 = blockIdx.y * 196;
  float s = 0.f;
  for (int n = n0; n < n0 + 196; ++n)
    s += __bfloat162float(xb[(size_t)n * CIN + c]) * abar[b * NSP + n];
  atomicAdd(&xg[b * CIN + c], s);
}

// ---- K8a: ybar[b][d] = g_w[d,:] @ xg[b,:] + g_b[d] -------------------------
__global__ __launch_bounds__(64) void k_ybar(const float* __restrict__ gw,
                                             const float* __restrict__ gb,
                                             const float* __restrict__ xg,
                                             float* __restrict__ syb) {
  const int d = blockIdx.x;          // 512 blocks
  const int lane = threadIdx.x;
  const float4* wr = (const float4*)(gw + (size_t)d * CIN);
  float4 wv[4];
#pragma unroll
  for (int k = 0; k < 4; ++k) wv[k] = wr[k * 64 + lane];
  const float bv = gb[d];
#pragma unroll 1
  for (int b = 0; b < BATCH; ++b) {
    const float4* xr = (const float4*)(xg + (size_t)b * CIN);
    float s = 0.f;
#pragma unroll
    for (int k = 0; k < 4; ++k) {
      const float4 xv = xr[k * 64 + lane];
      s += wv[k].x * xv.x + wv[k].y * xv.y + wv[k].z * xv.z + wv[k].w * xv.w;
    }
    s = wave_sum(s);
    if (lane == 0) syb[b * CINT + d] = s + bv;
  }
}

// ---- K8b: spool[b][c] = xbar + w_b + w_w[c,:] @ ybar[b,:] ------------------
__global__ __launch_bounds__(64) void k_spool(const float* __restrict__ ww,
                                              const float* __restrict__ wbias,
                                              const float* __restrict__ xbar,
                                              const float* __restrict__ syb,
                                              float* __restrict__ spool) {
  const int c = blockIdx.x;          // 1024 blocks
  const int lane = threadIdx.x;
  const float4* wr = (const float4*)(ww + (size_t)c * CINT);
  float4 wv[2];
#pragma unroll
  for (int k = 0; k < 2; ++k) wv[k] = wr[k * 64 + lane];
  const float bv = wbias[c];
#pragma unroll 1
  for (int b = 0; b < BATCH; ++b) {
    const float4* yr = (const float4*)(syb + (size_t)b * CINT);
    float s = 0.f;
#pragma unroll
    for (int k = 0; k < 2; ++k) {
      const float4 yv = yr[k * 64 + lane];
      s += wv[k].x * yv.x + wv[k].y * yv.y + wv[k].z * yv.z + wv[k].w * yv.w;
    }
    s = wave_sum(s);
    if (lane == 0) spool[b * CIN + c] = s + bv + xbar[b * CIN + c];
  }
}

// ---- K8c: out = spool @ fc_w^T + fc_b --------------------------------------
__global__ __launch_bounds__(64) void k_out(const float* __restrict__ spool,
                                            const float* __restrict__ fcw,
                                            const float* __restrict__ fcb,
                                            float* __restrict__ out) {
  const int b = blockIdx.x;          // 16 blocks
  const int lane = threadIdx.x;
  const float4* pr = (const float4*)(spool + (size_t)b * CIN);
  float4 pv[4];
#pragma unroll
  for (int k = 0; k < 4; ++k) pv[k] = pr[k * 64 + lane];
#pragma unroll 1
  for (int cls = 0; cls < NCLS; ++cls) {
    const float4* wr = (const float4*)(fcw + (size_t)cls * CIN);
    float s = 0.f;
#pragma unroll
    for (int k = 0; k < 4; ++k) {
      const float4 wv = wr[k * 64 + lane];
      s += wv.x * pv[k].x + wv.y * pv[k].y + wv.z * pv[k].z + wv.w * pv[k].w;
    }
    s = wave_sum(s);
    if (lane == 0) out[b * NCLS + cls] = s + fcb[cls];
  }
}

// ---------------------------------------------------------------------------
extern "C" void kernel_launch(void* const* d_in, const int* in_sizes, int n_in,
                              void* d_out, int out_size, void* d_ws, size_t ws_size,
                              hipStream_t stream) {
  const float* x    = (const float*)d_in[0];
  const float* g_w  = (const float*)d_in[1];
  const float* g_b  = (const float*)d_in[2];
  const float* th_w = (const float*)d_in[3];
  const float* th_b = (const float*)d_in[4];
  const float* ph_w = (const float*)d_in[5];
  const float* ph_b = (const float*)d_in[6];
  const float* w_w  = (const float*)d_in[7];
  const float* w_b  = (const float*)d_in[8];
  const float* fc_w = (const float*)d_in[9];
  const float* fc_b = (const float*)d_in[10];
  float* out = (float*)d_out;

  char* ws = (char*)d_ws;
  size_t off = 0;
  auto carve = [&](size_t bytes) {
    void* p = ws + off;
    off = (off + bytes + 255) & ~(size_t)255;
    return p;
  };
  bf16*  xt    = (bf16*)carve((size_t)BATCH * NPAD * CIN * 2);    // 54.5 MB
  bf16*  wb    = (bf16*)carve((size_t)1024 * 1024 * 2);           //  2 MB
  bf16*  th    = (bf16*)carve((size_t)BATCH * NPAD * CINT * 2);   // 27.3 MB
  bf16*  ph    = (bf16*)carve((size_t)BATCH * NPAD * CINT * 2);   // 27.3 MB
  bf16*  eb    = (bf16*)carve((size_t)BATCH * NPAD * NPAD * 2);   // 88.6 MB
  float* psum  = (float*)carve((size_t)BATCH * NTIL * NPAD * 4);  //  1.4 MB
  float* rinv  = (float*)carve((size_t)BATCH * NSP * 4);
  float* abar  = (float*)carve((size_t)BATCH * NSP * 4);
  float* xbar  = (float*)carve((size_t)BATCH * CIN * 4);
  float* xg    = (float*)carve((size_t)BATCH * CIN * 4);
  float* syb   = (float*)carve((size_t)BATCH * CINT * 4);
  float* spool = (float*)carve((size_t)BATCH * CIN * 4);
  (void)ws_size; (void)in_sizes; (void)n_in; (void)out_size;

  hipMemsetAsync(abar, 0, (size_t)BATCH * NSP * 4, stream);
  hipMemsetAsync(xbar, 0, (size_t)BATCH * CIN * 4, stream);
  hipMemsetAsync(xg,   0, (size_t)BATCH * CIN * 4, stream);

  k_transpose<<<dim3(52, 8, 16), 256, 0, stream>>>(x, xt, xbar);
  k_wconv<<<1024, 256, 0, stream>>>(th_w, ph_w, wb);
  k_proj<<<dim3(8, 208), 256, 0, stream>>>(xt, wb, th_b, ph_b, th, ph);
  k_fgemm<<<dim3(13, 13, 16), 256, 0, stream>>>(th, ph, eb, psum);
  k_recip<<<98, 256, 0, stream>>>(psum, rinv);
  k_abar<<<dim3(7, 8, 16), 256, 0, stream>>>(eb, rinv, abar);
  k_xg<<<dim3(4, 8, 16), 256, 0, stream>>>(xt, abar, xg);
  k_ybar<<<512, 64, 0, stream>>>(g_w, g_b, xg, syb);
  k_spool<<<1024, 64, 0, stream>>>(w_w, w_b, xbar, syb, spool);
  k_out<<<16, 64, 0, stream>>>(spool, fc_w, fc_b, out);
}

// Round 5
// 344.892 us; speedup vs baseline: 1.4196x; 1.0315x over previous
//
#include <hip/hip_runtime.h>
#include <hip/hip_bf16.h>

// ---------------------------------------------------------------------------
// NonLocal block + FC, MI355X (gfx950).
// out = (mean_n(x) + w_w @ ybar + w_b) @ fc_w^T + fc_b
//   ybar = g_w @ xg + g_b ;  xg[b,c] = sum_n abar[b,n] x[b,c,n]
//   abar[b,m] = mean_n softmax_row(f)[n,m],  f = theta @ phi^T
// |f| <~ 60 -> exp without max-subtraction is fp32-safe; e stored bf16.
// R5: XCD-aware block remaps (A-tile consumers share one XCD L2) +
//     16 KB LDS epilogues (two 64-row staging halves) for occupancy.
// ---------------------------------------------------------------------------

#define BATCH 16
#define CIN   1024
#define CINT  512
#define NSP   1568      // 8*14*14
#define NPAD  1664      // 13*128
#define NTIL  13
#define NCLS  13

using bf16 = __hip_bfloat16;
typedef __attribute__((ext_vector_type(8))) short short8;
typedef __attribute__((ext_vector_type(4))) float f32x4;

#define DEVI static __device__ __forceinline__

DEVI void gload16(const void* g, void* l) {
  __builtin_amdgcn_global_load_lds((const __attribute__((address_space(1))) void*)g,
                                   (__attribute__((address_space(3))) void*)l, 16, 0, 0);
}

DEVI float wave_sum(float v) {
#pragma unroll
  for (int m = 32; m; m >>= 1) v += __shfl_xor(v, m);
  return v;
}

DEVI short f2bf(float f) {
  union { __hip_bfloat16 h; short s; } u;
  u.h = __float2bfloat16(f);
  return u.s;
}

// ---- K1: transpose x[b][c][n] fp32 -> xt[b][n][c] bf16, fused xbar ---------
// grid (52, 8, 16) block 256. n-tiles >= 49 are all-pad (zero-filled).
__global__ __launch_bounds__(256) void k_transpose(const float* __restrict__ x,
                                                   bf16* __restrict__ xt,
                                                   float* __restrict__ xbar) {
  __shared__ float t[128 * 37];
  const int b = blockIdx.z;
  const int n0 = blockIdx.x * 32;
  const int c0 = blockIdx.y * 128;
  const int tid = threadIdx.x;
  const int lane = tid & 63;
  const float* xb = x + (size_t)b * CIN * NSP;
  const bool pad = (n0 >= NSP);
#pragma unroll
  for (int it = 0; it < 4; ++it) {
    const int slot = it * 256 + tid;
    const int cr = slot >> 3;       // 0..127
    const int q = slot & 7;         // 0..7
    float4 v = {0.f, 0.f, 0.f, 0.f};
    if (!pad) v = *(const float4*)(xb + (size_t)(c0 + cr) * NSP + n0 + q * 4);
    t[cr * 37 + q * 4 + 0] = v.x;
    t[cr * 37 + q * 4 + 1] = v.y;
    t[cr * 37 + q * 4 + 2] = v.z;
    t[cr * 37 + q * 4 + 3] = v.w;
    // fused xbar partial: reduce over the 8 q-lanes (lane bits 0..2)
    float s = v.x + v.y + v.z + v.w;
    s += __shfl_xor(s, 1);
    s += __shfl_xor(s, 2);
    s += __shfl_xor(s, 4);
    if ((lane & 7) == 0 && !pad)
      atomicAdd(&xbar[b * CIN + c0 + cr], s * (1.0f / NSP));
  }
  __syncthreads();
  bf16* xo = xt + (size_t)b * NPAD * CIN;
#pragma unroll
  for (int it = 0; it < 2; ++it) {
    const int slot = it * 256 + tid;
    const int n = slot >> 4;        // 0..31
    const int seg = slot & 15;      // 0..15
    short8 o;
#pragma unroll
    for (int k = 0; k < 8; ++k) o[k] = f2bf(t[(seg * 8 + k) * 37 + n]);
    *(short8*)(xo + (size_t)(n0 + n) * CIN + c0 + seg * 8) = o;
  }
}

// ---- K1b: theta_w / phi_w fp32 -> wb bf16 [1024][1024] ---------------------
__global__ void k_wconv(const float* __restrict__ thw, const float* __restrict__ phw,
                        bf16* __restrict__ wb) {
  const int i4 = (blockIdx.x * 256 + threadIdx.x) * 4;
  const float* s = (i4 < 512 * 1024) ? (thw + i4) : (phw + (i4 - 512 * 1024));
  const float4 v = *(const float4*)s;
  wb[i4 + 0] = __float2bfloat16(v.x);
  wb[i4 + 1] = __float2bfloat16(v.y);
  wb[i4 + 2] = __float2bfloat16(v.z);
  wb[i4 + 3] = __float2bfloat16(v.w);
}

// ---- shared 128x128 bf16 BT-GEMM core (m97 structure) ----------------------
template <int LDK>
DEVI void gemm128_bt(const bf16* Ag, const bf16* Bg, bf16* lA, bf16* lB,
                     f32x4 acc[4][4]) {
  const int tid = threadIdx.x;
  const int lane = tid & 63;
  const int w = tid >> 6;
  const int wr = (w >> 1) * 64;
  const int wc = (w & 1) * 64;
#pragma unroll 1
  for (int ks = 0; ks < LDK / 32; ++ks) {
#pragma unroll
    for (int it = 0; it < 2; ++it) {
      const int ch = w * 64 + it * 256 + lane;
      const int row = ch >> 2;
      const int kc = ch & 3;
      const int lbase = (w * 64 + it * 256) * 8;
      gload16(Ag + (size_t)row * LDK + ks * 32 + kc * 8, lA + lbase);
      gload16(Bg + (size_t)row * LDK + ks * 32 + kc * 8, lB + lbase);
    }
    __syncthreads();
    short8 af[4], bfr[4];
#pragma unroll
    for (int i = 0; i < 4; ++i)
      af[i] = *(const short8*)(lA + (wr + i * 16 + (lane & 15)) * 32 + (lane >> 4) * 8);
#pragma unroll
    for (int i = 0; i < 4; ++i)
      bfr[i] = *(const short8*)(lB + (wc + i * 16 + (lane & 15)) * 32 + (lane >> 4) * 8);
#pragma unroll
    for (int m = 0; m < 4; ++m)
#pragma unroll
      for (int n = 0; n < 4; ++n)
        acc[m][n] = __builtin_amdgcn_mfma_f32_16x16x32_bf16(af[m], bfr[n], acc[m][n], 0, 0, 0);
    __syncthreads();
  }
}

// ---- K3: theta/phi projections. 1-D grid 1664, XCD-aware decode ------------
// All 8 consumers (bo) of A-tile bm get consecutive ids within one mod-8
// residue class -> same XCD -> A fetched once per tile.
__global__ __launch_bounds__(256) void k_proj(const bf16* __restrict__ xt,
                                              const bf16* __restrict__ wb,
                                              const float* __restrict__ thb,
                                              const float* __restrict__ phb,
                                              bf16* __restrict__ th,
                                              bf16* __restrict__ ph) {
  __shared__ bf16 smem[8192];   // 16 KB: lA|lB in GEMM, 64x128 stage in epilogue
  const int id = blockIdx.x;          // 0..1663
  const int rcls = id & 7;
  const int q = id >> 3;              // 0..207
  const int bm = (q >> 3) * 8 + rcls; // 0..207, XCD = bm % 8
  const int bo = q & 7;               // 0..7

  f32x4 acc[4][4];
  const f32x4 z = {0.f, 0.f, 0.f, 0.f};
#pragma unroll
  for (int m = 0; m < 4; ++m)
#pragma unroll
    for (int n = 0; n < 4; ++n) acc[m][n] = z;

  gemm128_bt<CIN>(xt + (size_t)bm * 128 * CIN, wb + (size_t)bo * 128 * CIN,
                  smem, smem + 4096, acc);

  const int tid = threadIdx.x;
  const int lane = tid & 63;
  const int w = tid >> 6;
  const int wc = (w & 1) * 64;
  const int hsel = w >> 1;            // which 64-row half this wave owns
  const float* bias = (bo < 4) ? thb : phb;
  bf16* outb = (bo < 4) ? th : ph;
  const int obase = (bo & 3) * 128;
#pragma unroll
  for (int h = 0; h < 2; ++h) {
    __syncthreads();
    if (hsel == h) {
#pragma unroll
      for (int m = 0; m < 4; ++m)
#pragma unroll
        for (int n = 0; n < 4; ++n) {
          const int col_l = wc + n * 16 + (lane & 15);
          const float bv = bias[obase + col_l];
#pragma unroll
          for (int j = 0; j < 4; ++j) {
            const int lr = m * 16 + (lane >> 4) * 4 + j;   // 0..63
            smem[lr * 128 + (col_l ^ ((lr & 7) << 3))] =
                __float2bfloat16(acc[m][n][j] + bv);
          }
        }
    }
    __syncthreads();
#pragma unroll
    for (int it = 0; it < 4; ++it) {
      const int slot = it * 256 + tid;
      const int rr = slot >> 4;       // 0..63
      const int seg = slot & 15;
      const short8 v = *(const short8*)(smem + rr * 128 + ((seg ^ (rr & 7)) << 3));
      *(short8*)(outb + (size_t)(bm * 128 + h * 64 + rr) * CINT + obase + seg * 8) = v;
    }
  }
}

// ---- K4: e = exp(theta @ phi^T) bf16 + per-tile row sums -------------------
// 1-D grid 2704, XCD-aware decode: all 169 tiles of batches {b: b%8==r} on
// XCD r -> th[b]+ph[b] (3.4 MB) resident in that XCD's 4 MB L2.
__global__ __launch_bounds__(256) void k_fgemm(const bf16* __restrict__ th,
                                               const bf16* __restrict__ ph,
                                               bf16* __restrict__ eb,
                                               float* __restrict__ psum) {
  __shared__ bf16 smem[8192];
  __shared__ float rsum2[2][128];
  const int id = blockIdx.x;          // 0..2703
  const int rcls = id & 7;
  const int q = id >> 3;              // 0..337
  const int bloc = q / 169;           // 0..1
  const int t = q - bloc * 169;       // 0..168
  const int b = bloc * 8 + rcls;      // 0..15, XCD = b % 8
  const int bm = t / 13;
  const int bn = t - bm * 13;

  f32x4 acc[4][4];
  const f32x4 z = {0.f, 0.f, 0.f, 0.f};
#pragma unroll
  for (int m = 0; m < 4; ++m)
#pragma unroll
    for (int n = 0; n < 4; ++n) acc[m][n] = z;

  gemm128_bt<CINT>(th + ((size_t)b * NPAD + bm * 128) * CINT,
                   ph + ((size_t)b * NPAD + bn * 128) * CINT,
                   smem, smem + 4096, acc);

  const int tid = threadIdx.x;
  const int lane = tid & 63;
  const int w = tid >> 6;
  const int wc = (w & 1) * 64;
  const int hsel = w >> 1;
  bf16* ebb = eb + ((size_t)b * NPAD + bm * 128) * NPAD + bn * 128;
#pragma unroll
  for (int h = 0; h < 2; ++h) {
    __syncthreads();
    if (hsel == h) {
#pragma unroll
      for (int m = 0; m < 4; ++m)
#pragma unroll
        for (int j = 0; j < 4; ++j) {
          const int lr = m * 16 + (lane >> 4) * 4 + j;     // 0..63
          float ps = 0.f;
#pragma unroll
          for (int n = 0; n < 4; ++n) {
            const int col_l = wc + n * 16 + (lane & 15);
            const float ev = __expf(acc[m][n][j]);
            smem[lr * 128 + (col_l ^ ((lr & 7) << 3))] = __float2bfloat16(ev);
            if (bn * 128 + col_l < NSP) ps += ev;          // mask pad columns
          }
          ps += __shfl_xor(ps, 1);
          ps += __shfl_xor(ps, 2);
          ps += __shfl_xor(ps, 4);
          ps += __shfl_xor(ps, 8);
          if ((lane & 15) == 0) rsum2[w & 1][h * 64 + lr] = ps;
        }
    }
    __syncthreads();
#pragma unroll
    for (int it = 0; it < 4; ++it) {
      const int slot = it * 256 + tid;
      const int rr = slot >> 4;       // 0..63
      const int seg = slot & 15;
      const short8 v = *(const short8*)(smem + rr * 128 + ((seg ^ (rr & 7)) << 3));
      *(short8*)(ebb + (size_t)(h * 64 + rr) * NPAD + seg * 8) = v;
    }
  }
  if (tid < 128)
    psum[((size_t)b * NTIL + bn) * NPAD + bm * 128 + tid] =
        rsum2[0][tid] + rsum2[1][tid];
}

// ---- K5: rinv[b][n] = 1 / sum_t psum[b][t][n] ------------------------------
__global__ void k_recip(const float* __restrict__ psum, float* __restrict__ rinv) {
  const int id = blockIdx.x * 256 + threadIdx.x;   // 98*256 == 25088 exact
  const int b = id / NSP;
  const int n = id - b * NSP;
  float s = 0.f;
#pragma unroll
  for (int t = 0; t < NTIL; ++t) s += psum[((size_t)b * NTIL + t) * NPAD + n];
  rinv[id] = 1.0f / s;
}

// ---- K6: abar[b][m] = (1/N) sum_n e[n,m] * rinv[n] -------------------------
// grid (7, 8, 16)
__global__ void k_abar(const bf16* __restrict__ eb, const float* __restrict__ rinv,
                       float* __restrict__ abar) {
  const int m = blockIdx.x * 256 + threadIdx.x;
  const int b = blockIdx.z;
  const bool act = m < NSP;
  const bf16* fb = eb + (size_t)b * NPAD * NPAD;
  const int n0 = blockIdx.y * 196;
  float local = 0.f;
  for (int n = n0; n < n0 + 196; ++n) {
    const float iS = rinv[b * NSP + n];
    if (act) local += __bfloat162float(fb[(size_t)n * NPAD + m]) * iS;
  }
  if (act) atomicAdd(&abar[b * NSP + m], local * (1.0f / NSP));
}

// ---- K7: xg[b][c] = sum_n abar[b][n] * xt[b][n][c]  (bf16 source) ----------
// grid (4, 8, 16)
__global__ void k_xg(const bf16* __restrict__ xt, const float* __restrict__ abar,
                     float* __restrict__ xg) {
  const int c = blockIdx.x * 256 + threadIdx.x;
  const int b = blockIdx.z;
  const bf16* xb = xt + (size_t)b * NPAD * CIN;
  const int n0 = blockIdx.y * 196;
  float s = 0.f;
  for (int n = n0; n < n0 + 196; ++n)
    s += __bfloat162float(xb[(size_t)n * CIN + c]) * abar[b * NSP + n];
  atomicAdd(&xg[b * CIN + c], s);
}

// ---- K8a: ybar[b][d] = g_w[d,:] @ xg[b,:] + g_b[d] -------------------------
__global__ __launch_bounds__(64) void k_ybar(const float* __restrict__ gw,
                                             const float* __restrict__ gb,
                                             const float* __restrict__ xg,
                                             float* __restrict__ syb) {
  const int d = blockIdx.x;          // 512 blocks
  const int lane = threadIdx.x;
  const float4* wr = (const float4*)(gw + (size_t)d * CIN);
  float4 wv[4];
#pragma unroll
  for (int k = 0; k < 4; ++k) wv[k] = wr[k * 64 + lane];
  const float bv = gb[d];
#pragma unroll 1
  for (int b = 0; b < BATCH; ++b) {
    const float4* xr = (const float4*)(xg + (size_t)b * CIN);
    float s = 0.f;
#pragma unroll
    for (int k = 0; k < 4; ++k) {
      const float4 xv = xr[k * 64 + lane];
      s += wv[k].x * xv.x + wv[k].y * xv.y + wv[k].z * xv.z + wv[k].w * xv.w;
    }
    s = wave_sum(s);
    if (lane == 0) syb[b * CINT + d] = s + bv;
  }
}

// ---- K8b: spool[b][c] = xbar + w_b + w_w[c,:] @ ybar[b,:] ------------------
__global__ __launch_bounds__(64) void k_spool(const float* __restrict__ ww,
                                              const float* __restrict__ wbias,
                                              const float* __restrict__ xbar,
                                              const float* __restrict__ syb,
                                              float* __restrict__ spool) {
  const int c = blockIdx.x;          // 1024 blocks
  const int lane = threadIdx.x;
  const float4* wr = (const float4*)(ww + (size_t)c * CINT);
  float4 wv[2];
#pragma unroll
  for (int k = 0; k < 2; ++k) wv[k] = wr[k * 64 + lane];
  const float bv = wbias[c];
#pragma unroll 1
  for (int b = 0; b < BATCH; ++b) {
    const float4* yr = (const float4*)(syb + (size_t)b * CINT);
    float s = 0.f;
#pragma unroll
    for (int k = 0; k < 2; ++k) {
      const float4 yv = yr[k * 64 + lane];
      s += wv[k].x * yv.x + wv[k].y * yv.y + wv[k].z * yv.z + wv[k].w * yv.w;
    }
    s = wave_sum(s);
    if (lane == 0) spool[b * CIN + c] = s + bv + xbar[b * CIN + c];
  }
}

// ---- K8c: out = spool @ fc_w^T + fc_b --------------------------------------
__global__ __launch_bounds__(64) void k_out(const float* __restrict__ spool,
                                            const float* __restrict__ fcw,
                                            const float* __restrict__ fcb,
                                            float* __restrict__ out) {
  const int b = blockIdx.x;          // 16 blocks
  const int lane = threadIdx.x;
  const float4* pr = (const float4*)(spool + (size_t)b * CIN);
  float4 pv[4];
#pragma unroll
  for (int k = 0; k < 4; ++k) pv[k] = pr[k * 64 + lane];
#pragma unroll 1
  for (int cls = 0; cls < NCLS; ++cls) {
    const float4* wr = (const float4*)(fcw + (size_t)cls * CIN);
    float s = 0.f;
#pragma unroll
    for (int k = 0; k < 4; ++k) {
      const float4 wv = wr[k * 64 + lane];
      s += wv.x * pv[k].x + wv.y * pv[k].y + wv.z * pv[k].z + wv.w * pv[k].w;
    }
    s = wave_sum(s);
    if (lane == 0) out[b * NCLS + cls] = s + fcb[cls];
  }
}

// ---------------------------------------------------------------------------
extern "C" void kernel_launch(void* const* d_in, const int* in_sizes, int n_in,
                              void* d_out, int out_size, void* d_ws, size_t ws_size,
                              hipStream_t stream) {
  const float* x    = (const float*)d_in[0];
  const float* g_w  = (const float*)d_in[1];
  const float* g_b  = (const float*)d_in[2];
  const float* th_w = (const float*)d_in[3];
  const float* th_b = (const float*)d_in[4];
  const float* ph_w = (const float*)d_in[5];
  const float* ph_b = (const float*)d_in[6];
  const float* w_w  = (const float*)d_in[7];
  const float* w_b  = (const float*)d_in[8];
  const float* fc_w = (const float*)d_in[9];
  const float* fc_b = (const float*)d_in[10];
  float* out = (float*)d_out;

  char* ws = (char*)d_ws;
  size_t off = 0;
  auto carve = [&](size_t bytes) {
    void* p = ws + off;
    off = (off + bytes + 255) & ~(size_t)255;
    return p;
  };
  bf16*  xt    = (bf16*)carve((size_t)BATCH * NPAD * CIN * 2);    // 54.5 MB
  bf16*  wb    = (bf16*)carve((size_t)1024 * 1024 * 2);           //  2 MB
  bf16*  th    = (bf16*)carve((size_t)BATCH * NPAD * CINT * 2);   // 27.3 MB
  bf16*  ph    = (bf16*)carve((size_t)BATCH * NPAD * CINT * 2);   // 27.3 MB
  bf16*  eb    = (bf16*)carve((size_t)BATCH * NPAD * NPAD * 2);   // 88.6 MB
  float* psum  = (float*)carve((size_t)BATCH * NTIL * NPAD * 4);  //  1.4 MB
  float* rinv  = (float*)carve((size_t)BATCH * NSP * 4);
  float* abar  = (float*)carve((size_t)BATCH * NSP * 4);
  float* xbar  = (float*)carve((size_t)BATCH * CIN * 4);
  float* xg    = (float*)carve((size_t)BATCH * CIN * 4);
  float* syb   = (float*)carve((size_t)BATCH * CINT * 4);
  float* spool = (float*)carve((size_t)BATCH * CIN * 4);
  (void)ws_size; (void)in_sizes; (void)n_in; (void)out_size;

  hipMemsetAsync(abar, 0, (size_t)BATCH * NSP * 4, stream);
  hipMemsetAsync(xbar, 0, (size_t)BATCH * CIN * 4, stream);
  hipMemsetAsync(xg,   0, (size_t)BATCH * CIN * 4, stream);

  k_transpose<<<dim3(52, 8, 16), 256, 0, stream>>>(x, xt, xbar);
  k_wconv<<<1024, 256, 0, stream>>>(th_w, ph_w, wb);
  k_proj<<<1664, 256, 0, stream>>>(xt, wb, th_b, ph_b, th, ph);
  k_fgemm<<<2704, 256, 0, stream>>>(th, ph, eb, psum);
  k_recip<<<98, 256, 0, stream>>>(psum, rinv);
  k_abar<<<dim3(7, 8, 16), 256, 0, stream>>>(eb, rinv, abar);
  k_xg<<<dim3(4, 8, 16), 256, 0, stream>>>(xt, abar, xg);
  k_ybar<<<512, 64, 0, stream>>>(g_w, g_b, xg, syb);
  k_spool<<<1024, 64, 0, stream>>>(w_w, w_b, xbar, syb, spool);
  k_out<<<16, 64, 0, stream>>>(spool, fc_w, fc_b, out);
}

// Round 6
// 338.177 us; speedup vs baseline: 1.4478x; 1.0199x over previous
//
#include <hip/hip_runtime.h>
#include <hip/hip_bf16.h>

// ---------------------------------------------------------------------------
// NonLocal block + FC, MI355X (gfx950).
// out = (mean_n(x) + w_w @ ybar + w_b) @ fc_w^T + fc_b
//   ybar = g_w @ xg + g_b ;  xg[b,c] = sum_n abar[b,n] x[b,c,n]
//   abar[b,m] = mean_n softmax_row(f)[n,m],  f = theta @ phi^T
// |f| <~ 60 -> exp without max-subtraction is fp32-safe; e stored bf16.
// R5: XCD-aware block remaps + 16 KB LDS epilogues.
// R6: K-slot XOR swizzle in GEMM LDS tiles (pre-swizzled global source +
//     linear gload_lds dest + swizzled ds_read) -> 8-way bank conflict -> 2-way.
// ---------------------------------------------------------------------------

#define BATCH 16
#define CIN   1024
#define CINT  512
#define NSP   1568      // 8*14*14
#define NPAD  1664      // 13*128
#define NTIL  13
#define NCLS  13

using bf16 = __hip_bfloat16;
typedef __attribute__((ext_vector_type(8))) short short8;
typedef __attribute__((ext_vector_type(4))) float f32x4;

#define DEVI static __device__ __forceinline__

DEVI void gload16(const void* g, void* l) {
  __builtin_amdgcn_global_load_lds((const __attribute__((address_space(1))) void*)g,
                                   (__attribute__((address_space(3))) void*)l, 16, 0, 0);
}

DEVI float wave_sum(float v) {
#pragma unroll
  for (int m = 32; m; m >>= 1) v += __shfl_xor(v, m);
  return v;
}

DEVI short f2bf(float f) {
  union { __hip_bfloat16 h; short s; } u;
  u.h = __float2bfloat16(f);
  return u.s;
}

// ---- K1: transpose x[b][c][n] fp32 -> xt[b][n][c] bf16, fused xbar ---------
// grid (52, 8, 16) block 256. n-tiles >= 49 are all-pad (zero-filled).
__global__ __launch_bounds__(256) void k_transpose(const float* __restrict__ x,
                                                   bf16* __restrict__ xt,
                                                   float* __restrict__ xbar) {
  __shared__ float t[128 * 37];
  const int b = blockIdx.z;
  const int n0 = blockIdx.x * 32;
  const int c0 = blockIdx.y * 128;
  const int tid = threadIdx.x;
  const int lane = tid & 63;
  const float* xb = x + (size_t)b * CIN * NSP;
  const bool pad = (n0 >= NSP);
#pragma unroll
  for (int it = 0; it < 4; ++it) {
    const int slot = it * 256 + tid;
    const int cr = slot >> 3;       // 0..127
    const int q = slot & 7;         // 0..7
    float4 v = {0.f, 0.f, 0.f, 0.f};
    if (!pad) v = *(const float4*)(xb + (size_t)(c0 + cr) * NSP + n0 + q * 4);
    t[cr * 37 + q * 4 + 0] = v.x;
    t[cr * 37 + q * 4 + 1] = v.y;
    t[cr * 37 + q * 4 + 2] = v.z;
    t[cr * 37 + q * 4 + 3] = v.w;
    // fused xbar partial: reduce over the 8 q-lanes (lane bits 0..2)
    float s = v.x + v.y + v.z + v.w;
    s += __shfl_xor(s, 1);
    s += __shfl_xor(s, 2);
    s += __shfl_xor(s, 4);
    if ((lane & 7) == 0 && !pad)
      atomicAdd(&xbar[b * CIN + c0 + cr], s * (1.0f / NSP));
  }
  __syncthreads();
  bf16* xo = xt + (size_t)b * NPAD * CIN;
#pragma unroll
  for (int it = 0; it < 2; ++it) {
    const int slot = it * 256 + tid;
    const int n = slot >> 4;        // 0..31
    const int seg = slot & 15;      // 0..15
    short8 o;
#pragma unroll
    for (int k = 0; k < 8; ++k) o[k] = f2bf(t[(seg * 8 + k) * 37 + n]);
    *(short8*)(xo + (size_t)(n0 + n) * CIN + c0 + seg * 8) = o;
  }
}

// ---- K1b: theta_w / phi_w fp32 -> wb bf16 [1024][1024] ---------------------
__global__ void k_wconv(const float* __restrict__ thw, const float* __restrict__ phw,
                        bf16* __restrict__ wb) {
  const int i4 = (blockIdx.x * 256 + threadIdx.x) * 4;
  const float* s = (i4 < 512 * 1024) ? (thw + i4) : (phw + (i4 - 512 * 1024));
  const float4 v = *(const float4*)s;
  wb[i4 + 0] = __float2bfloat16(v.x);
  wb[i4 + 1] = __float2bfloat16(v.y);
  wb[i4 + 2] = __float2bfloat16(v.z);
  wb[i4 + 3] = __float2bfloat16(v.w);
}

// ---- shared 128x128 bf16 BT-GEMM core (m97 structure + R6 K-slot swizzle) --
// LDS slot (row, kc) holds global (row, kc ^ ((row>>1)&3)). Staging keeps the
// gload_lds dest LINEAR (HW requirement) and pre-swizzles the per-lane GLOBAL
// column; reads apply the same involution. Both reduce to lane-only terms.
template <int LDK>
DEVI void gemm128_bt(const bf16* Ag, const bf16* Bg, bf16* lA, bf16* lB,
                     f32x4 acc[4][4]) {
  const int tid = threadIdx.x;
  const int lane = tid & 63;
  const int w = tid >> 6;
  const int wr = (w >> 1) * 64;
  const int wc = (w & 1) * 64;
  // staging: ch=(w*64+it*256+lane), row=ch>>2, kc=ch&3, s(row)=(ch>>3)&3
  //   -> kc_src = (lane&3) ^ ((lane>>3)&3)   (base bits drop out)
  const int kc_src8 = ((lane & 3) ^ ((lane >> 3) & 3)) * 8;
  // read: row = .. + (lane&15), kc = lane>>4, s(row) = (lane>>1)&3
  const int kc_rd8 = (((lane >> 4) ^ ((lane >> 1) & 3))) * 8;
#pragma unroll 1
  for (int ks = 0; ks < LDK / 32; ++ks) {
#pragma unroll
    for (int it = 0; it < 2; ++it) {
      const int ch = w * 64 + it * 256 + lane;
      const int row = ch >> 2;
      const int lbase = (w * 64 + it * 256) * 8;   // wave-uniform LDS base
      gload16(Ag + (size_t)row * LDK + ks * 32 + kc_src8, lA + lbase);
      gload16(Bg + (size_t)row * LDK + ks * 32 + kc_src8, lB + lbase);
    }
    __syncthreads();
    short8 af[4], bfr[4];
#pragma unroll
    for (int i = 0; i < 4; ++i)
      af[i] = *(const short8*)(lA + (wr + i * 16 + (lane & 15)) * 32 + kc_rd8);
#pragma unroll
    for (int i = 0; i < 4; ++i)
      bfr[i] = *(const short8*)(lB + (wc + i * 16 + (lane & 15)) * 32 + kc_rd8);
#pragma unroll
    for (int m = 0; m < 4; ++m)
#pragma unroll
      for (int n = 0; n < 4; ++n)
        acc[m][n] = __builtin_amdgcn_mfma_f32_16x16x32_bf16(af[m], bfr[n], acc[m][n], 0, 0, 0);
    __syncthreads();
  }
}

// ---- K3: theta/phi projections. 1-D grid 1664, XCD-aware decode ------------
__global__ __launch_bounds__(256) void k_proj(const bf16* __restrict__ xt,
                                              const bf16* __restrict__ wb,
                                              const float* __restrict__ thb,
                                              const float* __restrict__ phb,
                                              bf16* __restrict__ th,
                                              bf16* __restrict__ ph) {
  __shared__ bf16 smem[8192];   // 16 KB: lA|lB in GEMM, 64x128 stage in epilogue
  const int id = blockIdx.x;          // 0..1663
  const int rcls = id & 7;
  const int q = id >> 3;              // 0..207
  const int bm = (q >> 3) * 8 + rcls; // 0..207, XCD = bm % 8
  const int bo = q & 7;               // 0..7

  f32x4 acc[4][4];
  const f32x4 z = {0.f, 0.f, 0.f, 0.f};
#pragma unroll
  for (int m = 0; m < 4; ++m)
#pragma unroll
    for (int n = 0; n < 4; ++n) acc[m][n] = z;

  gemm128_bt<CIN>(xt + (size_t)bm * 128 * CIN, wb + (size_t)bo * 128 * CIN,
                  smem, smem + 4096, acc);

  const int tid = threadIdx.x;
  const int lane = tid & 63;
  const int w = tid >> 6;
  const int wc = (w & 1) * 64;
  const int hsel = w >> 1;            // which 64-row half this wave owns
  const float* bias = (bo < 4) ? thb : phb;
  bf16* outb = (bo < 4) ? th : ph;
  const int obase = (bo & 3) * 128;
#pragma unroll
  for (int h = 0; h < 2; ++h) {
    __syncthreads();
    if (hsel == h) {
#pragma unroll
      for (int m = 0; m < 4; ++m)
#pragma unroll
        for (int n = 0; n < 4; ++n) {
          const int col_l = wc + n * 16 + (lane & 15);
          const float bv = bias[obase + col_l];
#pragma unroll
          for (int j = 0; j < 4; ++j) {
            const int lr = m * 16 + (lane >> 4) * 4 + j;   // 0..63
            smem[lr * 128 + (col_l ^ ((lr & 7) << 3))] =
                __float2bfloat16(acc[m][n][j] + bv);
          }
        }
    }
    __syncthreads();
#pragma unroll
    for (int it = 0; it < 4; ++it) {
      const int slot = it * 256 + tid;
      const int rr = slot >> 4;       // 0..63
      const int seg = slot & 15;
      const short8 v = *(const short8*)(smem + rr * 128 + ((seg ^ (rr & 7)) << 3));
      *(short8*)(outb + (size_t)(bm * 128 + h * 64 + rr) * CINT + obase + seg * 8) = v;
    }
  }
}

// ---- K4: e = exp(theta @ phi^T) bf16 + per-tile row sums -------------------
// 1-D grid 2704, XCD-aware decode: batches {b: b%8==r} on XCD r.
__global__ __launch_bounds__(256) void k_fgemm(const bf16* __restrict__ th,
                                               const bf16* __restrict__ ph,
                                               bf16* __restrict__ eb,
                                               float* __restrict__ psum) {
  __shared__ bf16 smem[8192];
  __shared__ float rsum2[2][128];
  const int id = blockIdx.x;          // 0..2703
  const int rcls = id & 7;
  const int q = id >> 3;              // 0..337
  const int bloc = q / 169;           // 0..1
  const int t = q - bloc * 169;       // 0..168
  const int b = bloc * 8 + rcls;      // 0..15, XCD = b % 8
  const int bm = t / 13;
  const int bn = t - bm * 13;

  f32x4 acc[4][4];
  const f32x4 z = {0.f, 0.f, 0.f, 0.f};
#pragma unroll
  for (int m = 0; m < 4; ++m)
#pragma unroll
    for (int n = 0; n < 4; ++n) acc[m][n] = z;

  gemm128_bt<CINT>(th + ((size_t)b * NPAD + bm * 128) * CINT,
                   ph + ((size_t)b * NPAD + bn * 128) * CINT,
                   smem, smem + 4096, acc);

  const int tid = threadIdx.x;
  const int lane = tid & 63;
  const int w = tid >> 6;
  const int wc = (w & 1) * 64;
  const int hsel = w >> 1;
  bf16* ebb = eb + ((size_t)b * NPAD + bm * 128) * NPAD + bn * 128;
#pragma unroll
  for (int h = 0; h < 2; ++h) {
    __syncthreads();
    if (hsel == h) {
#pragma unroll
      for (int m = 0; m < 4; ++m)
#pragma unroll
        for (int j = 0; j < 4; ++j) {
          const int lr = m * 16 + (lane >> 4) * 4 + j;     // 0..63
          float ps = 0.f;
#pragma unroll
          for (int n = 0; n < 4; ++n) {
            const int col_l = wc + n * 16 + (lane & 15);
            const float ev = __expf(acc[m][n][j]);
            smem[lr * 128 + (col_l ^ ((lr & 7) << 3))] = __float2bfloat16(ev);
            if (bn * 128 + col_l < NSP) ps += ev;          // mask pad columns
          }
          ps += __shfl_xor(ps, 1);
          ps += __shfl_xor(ps, 2);
          ps += __shfl_xor(ps, 4);
          ps += __shfl_xor(ps, 8);
          if ((lane & 15) == 0) rsum2[w & 1][h * 64 + lr] = ps;
        }
    }
    __syncthreads();
#pragma unroll
    for (int it = 0; it < 4; ++it) {
      const int slot = it * 256 + tid;
      const int rr = slot >> 4;       // 0..63
      const int seg = slot & 15;
      const short8 v = *(const short8*)(smem + rr * 128 + ((seg ^ (rr & 7)) << 3));
      *(short8*)(ebb + (size_t)(h * 64 + rr) * NPAD + seg * 8) = v;
    }
  }
  if (tid < 128)
    psum[((size_t)b * NTIL + bn) * NPAD + bm * 128 + tid] =
        rsum2[0][tid] + rsum2[1][tid];
}

// ---- K5: rinv[b][n] = 1 / sum_t psum[b][t][n] ------------------------------
__global__ void k_recip(const float* __restrict__ psum, float* __restrict__ rinv) {
  const int id = blockIdx.x * 256 + threadIdx.x;   // 98*256 == 25088 exact
  const int b = id / NSP;
  const int n = id - b * NSP;
  float s = 0.f;
#pragma unroll
  for (int t = 0; t < NTIL; ++t) s += psum[((size_t)b * NTIL + t) * NPAD + n];
  rinv[id] = 1.0f / s;
}

// ---- K6: abar[b][m] = (1/N) sum_n e[n,m] * rinv[n] -------------------------
// grid (7, 8, 16)
__global__ void k_abar(const bf16* __restrict__ eb, const float* __restrict__ rinv,
                       float* __restrict__ abar) {
  const int m = blockIdx.x * 256 + threadIdx.x;
  const int b = blockIdx.z;
  const bool act = m < NSP;
  const bf16* fb = eb + (size_t)b * NPAD * NPAD;
  const int n0 = blockIdx.y * 196;
  float local = 0.f;
  for (int n = n0; n < n0 + 196; ++n) {
    const float iS = rinv[b * NSP + n];
    if (act) local += __bfloat162float(fb[(size_t)n * NPAD + m]) * iS;
  }
  if (act) atomicAdd(&abar[b * NSP + m], local * (1.0f / NSP));
}

// ---- K7: xg[b][c] = sum_n abar[b][n] * xt[b][n][c]  (bf16 source) ----------
// grid (4, 8, 16)
__global__ void k_xg(const bf16* __restrict__ xt, const float* __restrict__ abar,
                     float* __restrict__ xg) {
  const int c = blockIdx.x * 256 + threadIdx.x;
  const int b = blockIdx.z;
  const bf16* xb = xt + (size_t)b * NPAD * CIN;
  const int n0 = blockIdx.y * 196;
  float s = 0.f;
  for (int n = n0; n < n0 + 196; ++n)
    s += __bfloat162float(xb[(size_t)n * CIN + c]) * abar[b * NSP + n];
  atomicAdd(&xg[b * CIN + c], s);
}

// ---- K8a: ybar[b][d] = g_w[d,:] @ xg[b,:] + g_b[d] -------------------------
__global__ __launch_bounds__(64) void k_ybar(const float* __restrict__ gw,
                                             const float* __restrict__ gb,
                                             const float* __restrict__ xg,
                                             float* __restrict__ syb) {
  const int d = blockIdx.x;          // 512 blocks
  const int lane = threadIdx.x;
  const float4* wr = (const float4*)(gw + (size_t)d * CIN);
  float4 wv[4];
#pragma unroll
  for (int k = 0; k < 4; ++k) wv[k] = wr[k * 64 + lane];
  const float bv = gb[d];
#pragma unroll 1
  for (int b = 0; b < BATCH; ++b) {
    const float4* xr = (const float4*)(xg + (size_t)b * CIN);
    float s = 0.f;
#pragma unroll
    for (int k = 0; k < 4; ++k) {
      const float4 xv = xr[k * 64 + lane];
      s += wv[k].x * xv.x + wv[k].y * xv.y + wv[k].z * xv.z + wv[k].w * xv.w;
    }
    s = wave_sum(s);
    if (lane == 0) syb[b * CINT + d] = s + bv;
  }
}

// ---- K8b: spool[b][c] = xbar + w_b + w_w[c,:] @ ybar[b,:] ------------------
__global__ __launch_bounds__(64) void k_spool(const float* __restrict__ ww,
                                              const float* __restrict__ wbias,
                                              const float* __restrict__ xbar,
                                              const float* __restrict__ syb,
                                              float* __restrict__ spool) {
  const int c = blockIdx.x;          // 1024 blocks
  const int lane = threadIdx.x;
  const float4* wr = (const float4*)(ww + (size_t)c * CINT);
  float4 wv[2];
#pragma unroll
  for (int k = 0; k < 2; ++k) wv[k] = wr[k * 64 + lane];
  const float bv = wbias[c];
#pragma unroll 1
  for (int b = 0; b < BATCH; ++b) {
    const float4* yr = (const float4*)(syb + (size_t)b * CINT);
    float s = 0.f;
#pragma unroll
    for (int k = 0; k < 2; ++k) {
      const float4 yv = yr[k * 64 + lane];
      s += wv[k].x * yv.x + wv[k].y * yv.y + wv[k].z * yv.z + wv[k].w * yv.w;
    }
    s = wave_sum(s);
    if (lane == 0) spool[b * CIN + c] = s + bv + xbar[b * CIN + c];
  }
}

// ---- K8c: out = spool @ fc_w^T + fc_b --------------------------------------
__global__ __launch_bounds__(64) void k_out(const float* __restrict__ spool,
                                            const float* __restrict__ fcw,
                                            const float* __restrict__ fcb,
                                            float* __restrict__ out) {
  const int b = blockIdx.x;          // 16 blocks
  const int lane = threadIdx.x;
  const float4* pr = (const float4*)(spool + (size_t)b * CIN);
  float4 pv[4];
#pragma unroll
  for (int k = 0; k < 4; ++k) pv[k] = pr[k * 64 + lane];
#pragma unroll 1
  for (int cls = 0; cls < NCLS; ++cls) {
    const float4* wr = (const float4*)(fcw + (size_t)cls * CIN);
    float s = 0.f;
#pragma unroll
    for (int k = 0; k < 4; ++k) {
      const float4 wv = wr[k * 64 + lane];
      s += wv.x * pv[k].x + wv.y * pv[k].y + wv.z * pv[k].z + wv.w * pv[k].w;
    }
    s = wave_sum(s);
    if (lane == 0) out[b * NCLS + cls] = s + fcb[cls];
  }
}

// ---------------------------------------------------------------------------
extern "C" void kernel_launch(void* const* d_in, const int* in_sizes, int n_in,
                              void* d_out, int out_size, void* d_ws, size_t ws_size,
                              hipStream_t stream) {
  const float* x    = (const float*)d_in[0];
  const float* g_w  = (const float*)d_in[1];
  const float* g_b  = (const float*)d_in[2];
  const float* th_w = (const float*)d_in[3];
  const float* th_b = (const float*)d_in[4];
  const float* ph_w = (const float*)d_in[5];
  const float* ph_b = (const float*)d_in[6];
  const float* w_w  = (const float*)d_in[7];
  const float* w_b  = (const float*)d_in[8];
  const float* fc_w = (const float*)d_in[9];
  const float* fc_b = (const float*)d_in[10];
  float* out = (float*)d_out;

  char* ws = (char*)d_ws;
  size_t off = 0;
  auto carve = [&](size_t bytes) {
    void* p = ws + off;
    off = (off + bytes + 255) & ~(size_t)255;
    return p;
  };
  bf16*  xt    = (bf16*)carve((size_t)BATCH * NPAD * CIN * 2);    // 54.5 MB
  bf16*  wb    = (bf16*)carve((size_t)1024 * 1024 * 2);           //  2 MB
  bf16*  th    = (bf16*)carve((size_t)BATCH * NPAD * CINT * 2);   // 27.3 MB
  bf16*  ph    = (bf16*)carve((size_t)BATCH * NPAD * CINT * 2);   // 27.3 MB
  bf16*  eb    = (bf16*)carve((size_t)BATCH * NPAD * NPAD * 2);   // 88.6 MB
  float* psum  = (float*)carve((size_t)BATCH * NTIL * NPAD * 4);  //  1.4 MB
  float* rinv  = (float*)carve((size_t)BATCH * NSP * 4);
  float* abar  = (float*)carve((size_t)BATCH * NSP * 4);
  float* xbar  = (float*)carve((size_t)BATCH * CIN * 4);
  float* xg    = (float*)carve((size_t)BATCH * CIN * 4);
  float* syb   = (float*)carve((size_t)BATCH * CINT * 4);
  float* spool = (float*)carve((size_t)BATCH * CIN * 4);
  (void)ws_size; (void)in_sizes; (void)n_in; (void)out_size;

  hipMemsetAsync(abar, 0, (size_t)BATCH * NSP * 4, stream);
  hipMemsetAsync(xbar, 0, (size_t)BATCH * CIN * 4, stream);
  hipMemsetAsync(xg,   0, (size_t)BATCH * CIN * 4, stream);

  k_transpose<<<dim3(52, 8, 16), 256, 0, stream>>>(x, xt, xbar);
  k_wconv<<<1024, 256, 0, stream>>>(th_w, ph_w, wb);
  k_proj<<<1664, 256, 0, stream>>>(xt, wb, th_b, ph_b, th, ph);
  k_fgemm<<<2704, 256, 0, stream>>>(th, ph, eb, psum);
  k_recip<<<98, 256, 0, stream>>>(psum, rinv);
  k_abar<<<dim3(7, 8, 16), 256, 0, stream>>>(eb, rinv, abar);
  k_xg<<<dim3(4, 8, 16), 256, 0, stream>>>(xt, abar, xg);
  k_ybar<<<512, 64, 0, stream>>>(g_w, g_b, xg, syb);
  k_spool<<<1024, 64, 0, stream>>>(w_w, w_b, xbar, syb, spool);
  k_out<<<16, 64, 0, stream>>>(spool, fc_w, fc_b, out);
}

// Round 7
// 311.651 us; speedup vs baseline: 1.5711x; 1.0851x over previous
//
#include <hip/hip_runtime.h>
#include <hip/hip_bf16.h>

// ---------------------------------------------------------------------------
// NonLocal block + FC, MI355X (gfx950).
// out = (mean_n(x) + w_w @ ybar + w_b) @ fc_w^T + fc_b
//   ybar = g_w @ xg + g_b ;  xg[b,c] = sum_n abar[b,n] x[b,c,n]
//   abar[b,m] = mean_n softmax_row(f)[n,m],  f = theta @ phi^T
// |f| <~ 60 -> exp without max-subtraction is fp32-safe; e stored bf16.
// R5: XCD-aware block remaps + 16 KB LDS epilogues.
// R6: K-slot XOR swizzle in GEMM LDS tiles -> bank conflicts 6.8M -> 0.
// R7: 2-phase double-buffered K-loop (STAGE t+1 before COMPUTE t, one
//     __syncthreads per K-step instead of two) -> hide staging latency.
// ---------------------------------------------------------------------------

#define BATCH 16
#define CIN   1024
#define CINT  512
#define NSP   1568      // 8*14*14
#define NPAD  1664      // 13*128
#define NTIL  13
#define NCLS  13

using bf16 = __hip_bfloat16;
typedef __attribute__((ext_vector_type(8))) short short8;
typedef __attribute__((ext_vector_type(4))) float f32x4;

#define DEVI static __device__ __forceinline__

DEVI void gload16(const void* g, void* l) {
  __builtin_amdgcn_global_load_lds((const __attribute__((address_space(1))) void*)g,
                                   (__attribute__((address_space(3))) void*)l, 16, 0, 0);
}

DEVI float wave_sum(float v) {
#pragma unroll
  for (int m = 32; m; m >>= 1) v += __shfl_xor(v, m);
  return v;
}

DEVI short f2bf(float f) {
  union { __hip_bfloat16 h; short s; } u;
  u.h = __float2bfloat16(f);
  return u.s;
}

// ---- K1: transpose x[b][c][n] fp32 -> xt[b][n][c] bf16, fused xbar ---------
// grid (52, 8, 16) block 256. n-tiles >= 49 are all-pad (zero-filled).
__global__ __launch_bounds__(256) void k_transpose(const float* __restrict__ x,
                                                   bf16* __restrict__ xt,
                                                   float* __restrict__ xbar) {
  __shared__ float t[128 * 37];
  const int b = blockIdx.z;
  const int n0 = blockIdx.x * 32;
  const int c0 = blockIdx.y * 128;
  const int tid = threadIdx.x;
  const int lane = tid & 63;
  const float* xb = x + (size_t)b * CIN * NSP;
  const bool pad = (n0 >= NSP);
#pragma unroll
  for (int it = 0; it < 4; ++it) {
    const int slot = it * 256 + tid;
    const int cr = slot >> 3;       // 0..127
    const int q = slot & 7;         // 0..7
    float4 v = {0.f, 0.f, 0.f, 0.f};
    if (!pad) v = *(const float4*)(xb + (size_t)(c0 + cr) * NSP + n0 + q * 4);
    t[cr * 37 + q * 4 + 0] = v.x;
    t[cr * 37 + q * 4 + 1] = v.y;
    t[cr * 37 + q * 4 + 2] = v.z;
    t[cr * 37 + q * 4 + 3] = v.w;
    // fused xbar partial: reduce over the 8 q-lanes (lane bits 0..2)
    float s = v.x + v.y + v.z + v.w;
    s += __shfl_xor(s, 1);
    s += __shfl_xor(s, 2);
    s += __shfl_xor(s, 4);
    if ((lane & 7) == 0 && !pad)
      atomicAdd(&xbar[b * CIN + c0 + cr], s * (1.0f / NSP));
  }
  __syncthreads();
  bf16* xo = xt + (size_t)b * NPAD * CIN;
#pragma unroll
  for (int it = 0; it < 2; ++it) {
    const int slot = it * 256 + tid;
    const int n = slot >> 4;        // 0..31
    const int seg = slot & 15;      // 0..15
    short8 o;
#pragma unroll
    for (int k = 0; k < 8; ++k) o[k] = f2bf(t[(seg * 8 + k) * 37 + n]);
    *(short8*)(xo + (size_t)(n0 + n) * CIN + c0 + seg * 8) = o;
  }
}

// ---- K1b: theta_w / phi_w fp32 -> wb bf16 [1024][1024] ---------------------
__global__ void k_wconv(const float* __restrict__ thw, const float* __restrict__ phw,
                        bf16* __restrict__ wb) {
  const int i4 = (blockIdx.x * 256 + threadIdx.x) * 4;
  const float* s = (i4 < 512 * 1024) ? (thw + i4) : (phw + (i4 - 512 * 1024));
  const float4 v = *(const float4*)s;
  wb[i4 + 0] = __float2bfloat16(v.x);
  wb[i4 + 1] = __float2bfloat16(v.y);
  wb[i4 + 2] = __float2bfloat16(v.z);
  wb[i4 + 3] = __float2bfloat16(v.w);
}

// ---- shared 128x128 bf16 BT-GEMM core: R6 swizzle + R7 2-phase dbuf --------
// LDS slot (row, kc) holds global (row, kc ^ ((row>>1)&3)); staging keeps
// gload_lds dest LINEAR and pre-swizzles the per-lane GLOBAL column; reads
// apply the same involution (lane-only expressions, zero extra VALU).
// Double buffer: lds[0..8191] = buf0 (A|B), lds[8192..16383] = buf1 (A|B).
// One __syncthreads per K-step: drains vmcnt(0) for STAGE(t+1) and
// cross-wave lgkm for reads of buf[t] before t+1 overwrites it at t+2.
template <int LDK>
DEVI void gemm128_bt(const bf16* Ag, const bf16* Bg, bf16* lds,
                     f32x4 acc[4][4]) {
  const int tid = threadIdx.x;
  const int lane = tid & 63;
  const int w = tid >> 6;
  const int wr = (w >> 1) * 64;
  const int wc = (w & 1) * 64;
  const int kc_src8 = ((lane & 3) ^ ((lane >> 3) & 3)) * 8;
  const int kc_rd8 = (((lane >> 4) ^ ((lane >> 1) & 3))) * 8;
  constexpr int NT = LDK / 32;   // 32 (proj) or 16 (fgemm), even

  auto STAGE = [&](int buf, int ks) {
    bf16* lA = lds + buf * 8192;
    bf16* lB = lA + 4096;
#pragma unroll
    for (int it = 0; it < 2; ++it) {
      const int ch = w * 64 + it * 256 + lane;
      const int row = ch >> 2;
      const int lbase = (w * 64 + it * 256) * 8;   // wave-uniform LDS base
      gload16(Ag + (size_t)row * LDK + ks * 32 + kc_src8, lA + lbase);
      gload16(Bg + (size_t)row * LDK + ks * 32 + kc_src8, lB + lbase);
    }
  };
  auto COMPUTE = [&](int buf) {
    const bf16* lA = lds + buf * 8192;
    const bf16* lB = lA + 4096;
    short8 af[4], bfr[4];
#pragma unroll
    for (int i = 0; i < 4; ++i)
      af[i] = *(const short8*)(lA + (wr + i * 16 + (lane & 15)) * 32 + kc_rd8);
#pragma unroll
    for (int i = 0; i < 4; ++i)
      bfr[i] = *(const short8*)(lB + (wc + i * 16 + (lane & 15)) * 32 + kc_rd8);
#pragma unroll
    for (int m = 0; m < 4; ++m)
#pragma unroll
      for (int n = 0; n < 4; ++n)
        acc[m][n] = __builtin_amdgcn_mfma_f32_16x16x32_bf16(af[m], bfr[n], acc[m][n], 0, 0, 0);
  };

  STAGE(0, 0);
  __syncthreads();
  int ks = 0;
#pragma unroll 1
  while (ks < NT - 2) {
    STAGE(1, ks + 1);
    COMPUTE(0);
    __syncthreads();
    STAGE(0, ks + 2);
    COMPUTE(1);
    __syncthreads();
    ks += 2;
  }
  // ks == NT-2 (NT even)
  STAGE(1, NT - 1);
  COMPUTE(0);
  __syncthreads();
  COMPUTE(1);
}

// ---- K3: theta/phi projections. 1-D grid 1664, XCD-aware decode ------------
__global__ __launch_bounds__(256) void k_proj(const bf16* __restrict__ xt,
                                              const bf16* __restrict__ wb,
                                              const float* __restrict__ thb,
                                              const float* __restrict__ phb,
                                              bf16* __restrict__ th,
                                              bf16* __restrict__ ph) {
  __shared__ bf16 smem[16384];  // 32 KB: dbuf in GEMM, 64x128 stage in epilogue
  const int id = blockIdx.x;          // 0..1663
  const int rcls = id & 7;
  const int q = id >> 3;              // 0..207
  const int bm = (q >> 3) * 8 + rcls; // 0..207, XCD = bm % 8
  const int bo = q & 7;               // 0..7

  f32x4 acc[4][4];
  const f32x4 z = {0.f, 0.f, 0.f, 0.f};
#pragma unroll
  for (int m = 0; m < 4; ++m)
#pragma unroll
    for (int n = 0; n < 4; ++n) acc[m][n] = z;

  gemm128_bt<CIN>(xt + (size_t)bm * 128 * CIN, wb + (size_t)bo * 128 * CIN,
                  smem, acc);

  const int tid = threadIdx.x;
  const int lane = tid & 63;
  const int w = tid >> 6;
  const int wc = (w & 1) * 64;
  const int hsel = w >> 1;            // which 64-row half this wave owns
  const float* bias = (bo < 4) ? thb : phb;
  bf16* outb = (bo < 4) ? th : ph;
  const int obase = (bo & 3) * 128;
#pragma unroll
  for (int h = 0; h < 2; ++h) {
    __syncthreads();
    if (hsel == h) {
#pragma unroll
      for (int m = 0; m < 4; ++m)
#pragma unroll
        for (int n = 0; n < 4; ++n) {
          const int col_l = wc + n * 16 + (lane & 15);
          const float bv = bias[obase + col_l];
#pragma unroll
          for (int j = 0; j < 4; ++j) {
            const int lr = m * 16 + (lane >> 4) * 4 + j;   // 0..63
            smem[lr * 128 + (col_l ^ ((lr & 7) << 3))] =
                __float2bfloat16(acc[m][n][j] + bv);
          }
        }
    }
    __syncthreads();
#pragma unroll
    for (int it = 0; it < 4; ++it) {
      const int slot = it * 256 + tid;
      const int rr = slot >> 4;       // 0..63
      const int seg = slot & 15;
      const short8 v = *(const short8*)(smem + rr * 128 + ((seg ^ (rr & 7)) << 3));
      *(short8*)(outb + (size_t)(bm * 128 + h * 64 + rr) * CINT + obase + seg * 8) = v;
    }
  }
}

// ---- K4: e = exp(theta @ phi^T) bf16 + per-tile row sums -------------------
// 1-D grid 2704, XCD-aware decode: batches {b: b%8==r} on XCD r.
__global__ __launch_bounds__(256) void k_fgemm(const bf16* __restrict__ th,
                                               const bf16* __restrict__ ph,
                                               bf16* __restrict__ eb,
                                               float* __restrict__ psum) {
  __shared__ bf16 smem[16384];
  __shared__ float rsum2[2][128];
  const int id = blockIdx.x;          // 0..2703
  const int rcls = id & 7;
  const int q = id >> 3;              // 0..337
  const int bloc = q / 169;           // 0..1
  const int t = q - bloc * 169;       // 0..168
  const int b = bloc * 8 + rcls;      // 0..15, XCD = b % 8
  const int bm = t / 13;
  const int bn = t - bm * 13;

  f32x4 acc[4][4];
  const f32x4 z = {0.f, 0.f, 0.f, 0.f};
#pragma unroll
  for (int m = 0; m < 4; ++m)
#pragma unroll
    for (int n = 0; n < 4; ++n) acc[m][n] = z;

  gemm128_bt<CINT>(th + ((size_t)b * NPAD + bm * 128) * CINT,
                   ph + ((size_t)b * NPAD + bn * 128) * CINT,
                   smem, acc);

  const int tid = threadIdx.x;
  const int lane = tid & 63;
  const int w = tid >> 6;
  const int wc = (w & 1) * 64;
  const int hsel = w >> 1;
  bf16* ebb = eb + ((size_t)b * NPAD + bm * 128) * NPAD + bn * 128;
#pragma unroll
  for (int h = 0; h < 2; ++h) {
    __syncthreads();
    if (hsel == h) {
#pragma unroll
      for (int m = 0; m < 4; ++m)
#pragma unroll
        for (int j = 0; j < 4; ++j) {
          const int lr = m * 16 + (lane >> 4) * 4 + j;     // 0..63
          float ps = 0.f;
#pragma unroll
          for (int n = 0; n < 4; ++n) {
            const int col_l = wc + n * 16 + (lane & 15);
            const float ev = __expf(acc[m][n][j]);
            smem[lr * 128 + (col_l ^ ((lr & 7) << 3))] = __float2bfloat16(ev);
            if (bn * 128 + col_l < NSP) ps += ev;          // mask pad columns
          }
          ps += __shfl_xor(ps, 1);
          ps += __shfl_xor(ps, 2);
          ps += __shfl_xor(ps, 4);
          ps += __shfl_xor(ps, 8);
          if ((lane & 15) == 0) rsum2[w & 1][h * 64 + lr] = ps;
        }
    }
    __syncthreads();
#pragma unroll
    for (int it = 0; it < 4; ++it) {
      const int slot = it * 256 + tid;
      const int rr = slot >> 4;       // 0..63
      const int seg = slot & 15;
      const short8 v = *(const short8*)(smem + rr * 128 + ((seg ^ (rr & 7)) << 3));
      *(short8*)(ebb + (size_t)(h * 64 + rr) * NPAD + seg * 8) = v;
    }
  }
  if (tid < 128)
    psum[((size_t)b * NTIL + bn) * NPAD + bm * 128 + tid] =
        rsum2[0][tid] + rsum2[1][tid];
}

// ---- K5: rinv[b][n] = 1 / sum_t psum[b][t][n] ------------------------------
__global__ void k_recip(const float* __restrict__ psum, float* __restrict__ rinv) {
  const int id = blockIdx.x * 256 + threadIdx.x;   // 98*256 == 25088 exact
  const int b = id / NSP;
  const int n = id - b * NSP;
  float s = 0.f;
#pragma unroll
  for (int t = 0; t < NTIL; ++t) s += psum[((size_t)b * NTIL + t) * NPAD + n];
  rinv[id] = 1.0f / s;
}

// ---- K6: abar[b][m] = (1/N) sum_n e[n,m] * rinv[n] -------------------------
// grid (7, 8, 16)
__global__ void k_abar(const bf16* __restrict__ eb, const float* __restrict__ rinv,
                       float* __restrict__ abar) {
  const int m = blockIdx.x * 256 + threadIdx.x;
  const int b = blockIdx.z;
  const bool act = m < NSP;
  const bf16* fb = eb + (size_t)b * NPAD * NPAD;
  const int n0 = blockIdx.y * 196;
  float local = 0.f;
  for (int n = n0; n < n0 + 196; ++n) {
    const float iS = rinv[b * NSP + n];
    if (act) local += __bfloat162float(fb[(size_t)n * NPAD + m]) * iS;
  }
  if (act) atomicAdd(&abar[b * NSP + m], local * (1.0f / NSP));
}

// ---- K7: xg[b][c] = sum_n abar[b][n] * xt[b][n][c]  (bf16 source) ----------
// grid (4, 8, 16)
__global__ void k_xg(const bf16* __restrict__ xt, const float* __restrict__ abar,
                     float* __restrict__ xg) {
  const int c = blockIdx.x * 256 + threadIdx.x;
  const int b = blockIdx.z;
  const bf16* xb = xt + (size_t)b * NPAD * CIN;
  const int n0 = blockIdx.y * 196;
  float s = 0.f;
  for (int n = n0; n < n0 + 196; ++n)
    s += __bfloat162float(xb[(size_t)n * CIN + c]) * abar[b * NSP + n];
  atomicAdd(&xg[b * CIN + c], s);
}

// ---- K8a: ybar[b][d] = g_w[d,:] @ xg[b,:] + g_b[d] -------------------------
__global__ __launch_bounds__(64) void k_ybar(const float* __restrict__ gw,
                                             const float* __restrict__ gb,
                                             const float* __restrict__ xg,
                                             float* __restrict__ syb) {
  const int d = blockIdx.x;          // 512 blocks
  const int lane = threadIdx.x;
  const float4* wr = (const float4*)(gw + (size_t)d * CIN);
  float4 wv[4];
#pragma unroll
  for (int k = 0; k < 4; ++k) wv[k] = wr[k * 64 + lane];
  const float bv = gb[d];
#pragma unroll 1
  for (int b = 0; b < BATCH; ++b) {
    const float4* xr = (const float4*)(xg + (size_t)b * CIN);
    float s = 0.f;
#pragma unroll
    for (int k = 0; k < 4; ++k) {
      const float4 xv = xr[k * 64 + lane];
      s += wv[k].x * xv.x + wv[k].y * xv.y + wv[k].z * xv.z + wv[k].w * xv.w;
    }
    s = wave_sum(s);
    if (lane == 0) syb[b * CINT + d] = s + bv;
  }
}

// ---- K8b: spool[b][c] = xbar + w_b + w_w[c,:] @ ybar[b,:] ------------------
__global__ __launch_bounds__(64) void k_spool(const float* __restrict__ ww,
                                              const float* __restrict__ wbias,
                                              const float* __restrict__ xbar,
                                              const float* __restrict__ syb,
                                              float* __restrict__ spool) {
  const int c = blockIdx.x;          // 1024 blocks
  const int lane = threadIdx.x;
  const float4* wr = (const float4*)(ww + (size_t)c * CINT);
  float4 wv[2];
#pragma unroll
  for (int k = 0; k < 2; ++k) wv[k] = wr[k * 64 + lane];
  const float bv = wbias[c];
#pragma unroll 1
  for (int b = 0; b < BATCH; ++b) {
    const float4* yr = (const float4*)(syb + (size_t)b * CINT);
    float s = 0.f;
#pragma unroll
    for (int k = 0; k < 2; ++k) {
      const float4 yv = yr[k * 64 + lane];
      s += wv[k].x * yv.x + wv[k].y * yv.y + wv[k].z * yv.z + wv[k].w * yv.w;
    }
    s = wave_sum(s);
    if (lane == 0) spool[b * CIN + c] = s + bv + xbar[b * CIN + c];
  }
}

// ---- K8c: out = spool @ fc_w^T + fc_b --------------------------------------
__global__ __launch_bounds__(64) void k_out(const float* __restrict__ spool,
                                            const float* __restrict__ fcw,
                                            const float* __restrict__ fcb,
                                            float* __restrict__ out) {
  const int b = blockIdx.x;          // 16 blocks
  const int lane = threadIdx.x;
  const float4* pr = (const float4*)(spool + (size_t)b * CIN);
  float4 pv[4];
#pragma unroll
  for (int k = 0; k < 4; ++k) pv[k] = pr[k * 64 + lane];
#pragma unroll 1
  for (int cls = 0; cls < NCLS; ++cls) {
    const float4* wr = (const float4*)(fcw + (size_t)cls * CIN);
    float s = 0.f;
#pragma unroll
    for (int k = 0; k < 4; ++k) {
      const float4 wv = wr[k * 64 + lane];
      s += wv.x * pv[k].x + wv.y * pv[k].y + wv.z * pv[k].z + wv.w * pv[k].w;
    }
    s = wave_sum(s);
    if (lane == 0) out[b * NCLS + cls] = s + fcb[cls];
  }
}

// ---------------------------------------------------------------------------
extern "C" void kernel_launch(void* const* d_in, const int* in_sizes, int n_in,
                              void* d_out, int out_size, void* d_ws, size_t ws_size,
                              hipStream_t stream) {
  const float* x    = (const float*)d_in[0];
  const float* g_w  = (const float*)d_in[1];
  const float* g_b  = (const float*)d_in[2];
  const float* th_w = (const float*)d_in[3];
  const float* th_b = (const float*)d_in[4];
  const float* ph_w = (const float*)d_in[5];
  const float* ph_b = (const float*)d_in[6];
  const float* w_w  = (const float*)d_in[7];
  const float* w_b  = (const float*)d_in[8];
  const float* fc_w = (const float*)d_in[9];
  const float* fc_b = (const float*)d_in[10];
  float* out = (float*)d_out;

  char* ws = (char*)d_ws;
  size_t off = 0;
  auto carve = [&](size_t bytes) {
    void* p = ws + off;
    off = (off + bytes + 255) & ~(size_t)255;
    return p;
  };
  bf16*  xt    = (bf16*)carve((size_t)BATCH * NPAD * CIN * 2);    // 54.5 MB
  bf16*  wb    = (bf16*)carve((size_t)1024 * 1024 * 2);           //  2 MB
  bf16*  th    = (bf16*)carve((size_t)BATCH * NPAD * CINT * 2);   // 27.3 MB
  bf16*  ph    = (bf16*)carve((size_t)BATCH * NPAD * CINT * 2);   // 27.3 MB
  bf16*  eb    = (bf16*)carve((size_t)BATCH * NPAD * NPAD * 2);   // 88.6 MB
  float* psum  = (float*)carve((size_t)BATCH * NTIL * NPAD * 4);  //  1.4 MB
  float* rinv  = (float*)carve((size_t)BATCH * NSP * 4);
  float* abar  = (float*)carve((size_t)BATCH * NSP * 4);
  float* xbar  = (float*)carve((size_t)BATCH * CIN * 4);
  float* xg    = (float*)carve((size_t)BATCH * CIN * 4);
  float* syb   = (float*)carve((size_t)BATCH * CINT * 4);
  float* spool = (float*)carve((size_t)BATCH * CIN * 4);
  (void)ws_size; (void)in_sizes; (void)n_in; (void)out_size;

  hipMemsetAsync(abar, 0, (size_t)BATCH * NSP * 4, stream);
  hipMemsetAsync(xbar, 0, (size_t)BATCH * CIN * 4, stream);
  hipMemsetAsync(xg,   0, (size_t)BATCH * CIN * 4, stream);

  k_transpose<<<dim3(52, 8, 16), 256, 0, stream>>>(x, xt, xbar);
  k_wconv<<<1024, 256, 0, stream>>>(th_w, ph_w, wb);
  k_proj<<<1664, 256, 0, stream>>>(xt, wb, th_b, ph_b, th, ph);
  k_fgemm<<<2704, 256, 0, stream>>>(th, ph, eb, psum);
  k_recip<<<98, 256, 0, stream>>>(psum, rinv);
  k_abar<<<dim3(7, 8, 16), 256, 0, stream>>>(eb, rinv, abar);
  k_xg<<<dim3(4, 8, 16), 256, 0, stream>>>(xt, abar, xg);
  k_ybar<<<512, 64, 0, stream>>>(g_w, g_b, xg, syb);
  k_spool<<<1024, 64, 0, stream>>>(w_w, w_b, xbar, syb, spool);
  k_out<<<16, 64, 0, stream>>>(spool, fc_w, fc_b, out);
}